// Round 16
// baseline (163.229 us; speedup 1.0000x reference)
//
#include <hip/hip_runtime.h>
#include <math.h>
#include <stdint.h>

#define B 4
#define T 8192
#define D 512
#define NN 256
#define L 768
#define TE 2048
#define H 8
#define DH 64
#define MR 64
#define AS 520          // Abuf row stride (bf16 elems)
#define SLICE 16384     // elems per 32-K staged B slice (512 cols * 32 k)
#define HS_RB 32768     // hS elems per 64-row block (16 kk * 4 mt * 512)

typedef __bf16 bf16;
typedef bf16  bf16x8 __attribute__((ext_vector_type(8)));
typedef float f32x4  __attribute__((ext_vector_type(4)));

__device__ __forceinline__ float sigmoidf_(float x){ return 1.0f/(1.0f+__expf(-x)); }

// ======== k_prep_all: kv [0,512) | weight re-layout [512,640) | ss [640,704) ========
__global__ __launch_bounds__(256) void k_prep_all(
    const float* __restrict__ xf, const float* __restrict__ Wk,
    const float* __restrict__ bk, const float* __restrict__ Wv,
    const float* __restrict__ bv, const float* __restrict__ tg,
    const float* __restrict__ tb, bf16* __restrict__ kbuf, bf16* __restrict__ vbuf,
    const float* __restrict__ Wq, const float* __restrict__ oW,
    bf16* __restrict__ wqS, bf16* __restrict__ owS,
    const float* __restrict__ emb, const float* __restrict__ emb_W,
    const float* __restrict__ emb_b, float* __restrict__ ss){
    __shared__ __align__(16) char smem[40960];
    const int bid = blockIdx.x, t = threadIdx.x;
    if (bid < 512){
        float (*xfn)[L] = (float(*)[L])smem;
        int g0 = (bid >> 2) * 8, jc = bid & 3;
        int wave = t >> 6, lane = t & 63;
        #pragma unroll
        for (int rr = 0; rr < 2; ++rr){
            int r = wave*2 + rr, g = g0 + r;
            float vals[12];
            float s = 0.f, sq = 0.f;
            #pragma unroll
            for (int i = 0; i < 12; ++i){ float v = xf[(size_t)g*L + lane*12 + i]; vals[i] = v; s += v; sq += v*v; }
            #pragma unroll
            for (int o = 32; o; o >>= 1){ s += __shfl_xor(s, o); sq += __shfl_xor(sq, o); }
            float m = s / L; float var = sq / L - m*m;
            float rstd = rsqrtf(var + 1e-5f);
            #pragma unroll
            for (int i = 0; i < 12; ++i){
                int l = lane*12 + i;
                xfn[r][l] = (vals[i]-m)*rstd*tg[l] + tb[l];
            }
        }
        __syncthreads();
        const float* Wm = (t < 128) ? Wk : Wv;
        int col = jc*128 + (t & 127);
        float acc[8];
        #pragma unroll
        for (int r = 0; r < 8; ++r) acc[r] = 0.f;
        for (int l = 0; l < L; l += 4){
            float4 xv[8];
            #pragma unroll
            for (int r = 0; r < 8; ++r) xv[r] = *(const float4*)&xfn[r][l];
            #pragma unroll
            for (int u = 0; u < 4; ++u){
                float wv = Wm[(size_t)(l+u)*D + col];
                #pragma unroll
                for (int r = 0; r < 8; ++r) acc[r] += ((const float*)&xv[r])[u] * wv;
            }
        }
        float bias = (t < 128) ? bk[col] : bv[col];
        bf16* dst = (t < 128) ? kbuf : vbuf;
        #pragma unroll
        for (int r = 0; r < 8; ++r){
            size_t g = (size_t)(g0 + r);
            dst[g*D + col] = (bf16)(acc[r] + bias);
        }
    } else if (bid < 640){
        int lb2 = bid - 512;
        const float* W = (lb2 < 64) ? Wq : oW;
        bf16* Wst = (lb2 < 64) ? wqS : owS;
        int lb = lb2 & 63;
        int k0 = (lb & 7)*64, n0 = (lb >> 3)*64;
        float (*tile)[65] = (float(*)[65])smem;
        int c = t & 63, r4 = t >> 6;
        #pragma unroll
        for (int p = 0; p < 16; ++p){ int r = p*4 + r4; tile[r][c] = W[(size_t)(k0+r)*D + n0 + c]; }
        __syncthreads();
        int oct = t >> 6, col = t & 63;
        #pragma unroll
        for (int half = 0; half < 2; ++half){
            int kk = (lb & 7)*2 + half;
            bf16x8 ov;
            #pragma unroll
            for (int j = 0; j < 8; ++j) ov[j] = (bf16)tile[half*32 + oct*8 + j][col];
            *(bf16x8*)&Wst[(size_t)kk*SLICE + (n0+col)*32 + oct*8] = ov;
        }
    } else {
        float (*semb)[TE] = (float(*)[TE])smem;
        float (*red)[64]  = (float(*)[64])(smem + 4*TE*4);
        int c = bid - 640;
        for (int i = t; i < TE; i += 256)
            #pragma unroll
            for (int b = 0; b < B; ++b){ float e = emb[b*TE + i]; semb[b][i] = e * sigmoidf_(e); }
        __syncthreads();
        int o = t & 15, p = t >> 4;
        int j = c*16 + o;
        float acc[B] = {0.f,0.f,0.f,0.f};
        for (int i = 0; i < 128; ++i){
            int e = p*128 + i;
            float wv = emb_W[(size_t)e*1024 + j];
            #pragma unroll
            for (int b = 0; b < B; ++b) acc[b] += semb[b][e] * wv;
        }
        #pragma unroll
        for (int b = 0; b < B; ++b) red[p][b*16 + o] = acc[b];
        __syncthreads();
        if (t < 64){
            int b = t >> 4, o2 = t & 15;
            int j2 = c*16 + o2;
            float s = 0.f;
            #pragma unroll
            for (int pp = 0; pp < 16; ++pp) s += red[pp][b*16 + o2];
            ss[b*1024 + j2] = s + emb_b[j2];
        }
    }
}

// ======== k_att: attn state, 512 threads ========
__global__ __launch_bounds__(512) void k_att(const bf16* __restrict__ kbuf,
                                             const bf16* __restrict__ vbuf,
                                             bf16* __restrict__ attF){
    __shared__ float kh[NN*DH];
    __shared__ float vh[NN*DH];
    __shared__ float pm[8][DH], ps[8][DH];
    int t = threadIdx.x, h = blockIdx.x, b = blockIdx.y;
    for (int k = 0; k < NN*DH/512; ++k){
        int m = k*512 + t;
        int n = m >> 6, dl = m & 63;
        size_t src = (size_t)(b*NN + n)*D + h*DH + dl;
        kh[m] = (float)kbuf[src]; vh[m] = (float)vbuf[src];
    }
    __syncthreads();
    int d = t & 63, c = t >> 6;
    float mx = -1e30f;
    for (int n = c*32; n < c*32+32; ++n) mx = fmaxf(mx, kh[n*DH + d]);
    pm[c][d] = mx;
    __syncthreads();
    mx = pm[0][d];
    #pragma unroll
    for (int cc = 1; cc < 8; ++cc) mx = fmaxf(mx, pm[cc][d]);
    float s = 0.f;
    for (int n = c*32; n < c*32+32; ++n){ float e = __expf(kh[n*DH + d] - mx); kh[n*DH + d] = e; s += e; }
    ps[c][d] = s;
    __syncthreads();
    float sden = ps[0][d];
    #pragma unroll
    for (int cc = 1; cc < 8; ++cc) sden += ps[cc][d];
    float inv = 1.f/sden;
    for (int n = c*32; n < c*32+32; ++n) kh[n*DH + d] *= inv;
    __syncthreads();
    int dl = t >> 3, dd0 = (t & 7)*8;
    float acc[8];
    #pragma unroll
    for (int i = 0; i < 8; ++i) acc[i] = 0.f;
    for (int n = 0; n < NN; ++n){
        float vv = vh[n*DH + dl];
        #pragma unroll
        for (int i = 0; i < 8; ++i) acc[i] += kh[n*DH + dd0 + i] * vv;
    }
    size_t hbase = ((size_t)(b*H + h)) << 12;
    int f  = (dl >> 4)*2 + (dd0 >> 5);
    int ln = ((dd0 >> 3) & 3)*16 + (dl & 15);
    bf16x8 ov;
    #pragma unroll
    for (int j = 0; j < 8; ++j) ov[j] = (bf16)acc[j];
    *(bf16x8*)&attF[hbase + f*512 + ln*8] = ov;
}

// ======== rolled GEMM, A from LDS (+T5 setprio) ========
__device__ __forceinline__ void gemm_body(const bf16* __restrict__ wfrag,
                                          const bf16* __restrict__ afrag,
                                          f32x4 (&acc)[4][4]){
    bf16x8 b0[4], b1[4];
    #pragma unroll
    for (int nt = 0; nt < 4; ++nt) b0[nt] = *(const bf16x8*)&wfrag[nt*512];
    #pragma unroll
    for (int nt = 0; nt < 4; ++nt) b1[nt] = *(const bf16x8*)&wfrag[SLICE + nt*512];
    const bf16* wp = wfrag + 2*(size_t)SLICE;
    const bf16* ap = afrag;
    __builtin_amdgcn_s_setprio(1);
    for (int kk = 0; kk < 14; kk += 2){
        bf16x8 aa[4];
        #pragma unroll
        for (int mt = 0; mt < 4; ++mt) aa[mt] = *(const bf16x8*)&ap[mt*16*AS];
        #pragma unroll
        for (int nt = 0; nt < 4; ++nt)
            #pragma unroll
            for (int mt = 0; mt < 4; ++mt)
                acc[mt][nt] = __builtin_amdgcn_mfma_f32_16x16x32_bf16(aa[mt], b0[nt], acc[mt][nt], 0, 0, 0);
        #pragma unroll
        for (int nt = 0; nt < 4; ++nt) b0[nt] = *(const bf16x8*)&wp[nt*512];
        #pragma unroll
        for (int mt = 0; mt < 4; ++mt) aa[mt] = *(const bf16x8*)&ap[mt*16*AS + 32];
        #pragma unroll
        for (int nt = 0; nt < 4; ++nt)
            #pragma unroll
            for (int mt = 0; mt < 4; ++mt)
                acc[mt][nt] = __builtin_amdgcn_mfma_f32_16x16x32_bf16(aa[mt], b1[nt], acc[mt][nt], 0, 0, 0);
        #pragma unroll
        for (int nt = 0; nt < 4; ++nt) b1[nt] = *(const bf16x8*)&wp[SLICE + nt*512];
        wp += 2*(size_t)SLICE; ap += 64;
    }
    {
        bf16x8 aa[4];
        #pragma unroll
        for (int mt = 0; mt < 4; ++mt) aa[mt] = *(const bf16x8*)&ap[mt*16*AS];
        #pragma unroll
        for (int nt = 0; nt < 4; ++nt)
            #pragma unroll
            for (int mt = 0; mt < 4; ++mt)
                acc[mt][nt] = __builtin_amdgcn_mfma_f32_16x16x32_bf16(aa[mt], b0[nt], acc[mt][nt], 0, 0, 0);
        #pragma unroll
        for (int mt = 0; mt < 4; ++mt) aa[mt] = *(const bf16x8*)&ap[mt*16*AS + 32];
        #pragma unroll
        for (int nt = 0; nt < 4; ++nt)
            #pragma unroll
            for (int mt = 0; mt < 4; ++mt)
                acc[mt][nt] = __builtin_amdgcn_mfma_f32_16x16x32_bf16(aa[mt], b1[nt], acc[mt][nt], 0, 0, 0);
    }
    __builtin_amdgcn_s_setprio(0);
}

// ======== rolled GEMM, BOTH operands from global (k_g2) ========
__device__ __forceinline__ void gemm_gg(const bf16* __restrict__ wfrag,
                                        const bf16* __restrict__ hfrag,
                                        f32x4 (&acc)[4][4]){
    bf16x8 b0[4], b1[4];
    #pragma unroll
    for (int nt = 0; nt < 4; ++nt) b0[nt] = *(const bf16x8*)&wfrag[nt*512];
    #pragma unroll
    for (int nt = 0; nt < 4; ++nt) b1[nt] = *(const bf16x8*)&wfrag[SLICE + nt*512];
    const bf16* wp = wfrag + 2*(size_t)SLICE;
    const bf16* hp = hfrag;
    __builtin_amdgcn_s_setprio(1);
    for (int kk = 0; kk < 14; kk += 2){
        bf16x8 aa[4];
        #pragma unroll
        for (int mt = 0; mt < 4; ++mt) aa[mt] = *(const bf16x8*)&hp[mt*512];
        #pragma unroll
        for (int nt = 0; nt < 4; ++nt)
            #pragma unroll
            for (int mt = 0; mt < 4; ++mt)
                acc[mt][nt] = __builtin_amdgcn_mfma_f32_16x16x32_bf16(aa[mt], b0[nt], acc[mt][nt], 0, 0, 0);
        #pragma unroll
        for (int nt = 0; nt < 4; ++nt) b0[nt] = *(const bf16x8*)&wp[nt*512];
        #pragma unroll
        for (int mt = 0; mt < 4; ++mt) aa[mt] = *(const bf16x8*)&hp[2048 + mt*512];
        #pragma unroll
        for (int nt = 0; nt < 4; ++nt)
            #pragma unroll
            for (int mt = 0; mt < 4; ++mt)
                acc[mt][nt] = __builtin_amdgcn_mfma_f32_16x16x32_bf16(aa[mt], b1[nt], acc[mt][nt], 0, 0, 0);
        #pragma unroll
        for (int nt = 0; nt < 4; ++nt) b1[nt] = *(const bf16x8*)&wp[SLICE + nt*512];
        wp += 2*(size_t)SLICE; hp += 4096;
    }
    {
        bf16x8 aa[4];
        #pragma unroll
        for (int mt = 0; mt < 4; ++mt) aa[mt] = *(const bf16x8*)&hp[mt*512];
        #pragma unroll
        for (int nt = 0; nt < 4; ++nt)
            #pragma unroll
            for (int mt = 0; mt < 4; ++mt)
                acc[mt][nt] = __builtin_amdgcn_mfma_f32_16x16x32_bf16(aa[mt], b0[nt], acc[mt][nt], 0, 0, 0);
        #pragma unroll
        for (int mt = 0; mt < 4; ++mt) aa[mt] = *(const bf16x8*)&hp[2048 + mt*512];
        #pragma unroll
        for (int nt = 0; nt < 4; ++nt)
            #pragma unroll
            for (int mt = 0; mt < 4; ++mt)
                acc[mt][nt] = __builtin_amdgcn_mfma_f32_16x16x32_bf16(aa[mt], b1[nt], acc[mt][nt], 0, 0, 0);
    }
    __builtin_amdgcn_s_setprio(0);
}

// ======== k_g1: LN -> GEMM1 -> softmax -> y -> stylize -> flush h (fragment order) ========
__global__ __launch_bounds__(512, 4) void k_g1(
    const float* __restrict__ x, const bf16* __restrict__ WqS, const float* __restrict__ bq,
    const float* __restrict__ lg, const float* __restrict__ lb,
    const bf16* __restrict__ attF, const float* __restrict__ ssb,
    const float* __restrict__ sg, const float* __restrict__ sb,
    bf16* __restrict__ hS){
    __shared__ __align__(16) bf16 Abuf[MR*AS];
    __shared__ float st_s[MR][8];
    __shared__ float st_q[MR][8];
    const int t = threadIdx.x, w = t >> 6, lane = t & 63;
    const int l15 = lane & 15, grp = lane >> 4;
    const long g0 = (long)blockIdx.x * MR;
    const int b = (int)(g0 / T);
    const int wb = w * 64;
    const size_t fragoff = (size_t)w*2048 + (size_t)l15*32 + (size_t)grp*8;

    // phase A: LN(x) -> Abuf
    {
        float4 lg0 = *(const float4*)&lg[lane*8], lg1 = *(const float4*)&lg[lane*8+4];
        float4 lb0 = *(const float4*)&lb[lane*8], lb1 = *(const float4*)&lb[lane*8+4];
        #pragma unroll 2
        for (int rr = 0; rr < 8; ++rr){
            int r = w*8 + rr;
            const float* xp = &x[(size_t)(g0 + r)*D + lane*8];
            float4 v0 = *(const float4*)xp, v1 = *(const float4*)(xp+4);
            float s  = v0.x+v0.y+v0.z+v0.w + v1.x+v1.y+v1.z+v1.w;
            float sq = v0.x*v0.x+v0.y*v0.y+v0.z*v0.z+v0.w*v0.w
                     + v1.x*v1.x+v1.y*v1.y+v1.z*v1.z+v1.w*v1.w;
            #pragma unroll
            for (int o = 32; o; o >>= 1){ s += __shfl_xor(s,o); sq += __shfl_xor(sq,o); }
            float m = s*(1.f/D), var = sq*(1.f/D) - m*m, rstd = rsqrtf(var + 1e-5f);
            bf16x8 ov;
            ov[0] = (bf16)((v0.x-m)*rstd*lg0.x + lb0.x);
            ov[1] = (bf16)((v0.y-m)*rstd*lg0.y + lb0.y);
            ov[2] = (bf16)((v0.z-m)*rstd*lg0.z + lb0.z);
            ov[3] = (bf16)((v0.w-m)*rstd*lg0.w + lb0.w);
            ov[4] = (bf16)((v1.x-m)*rstd*lg1.x + lb1.x);
            ov[5] = (bf16)((v1.y-m)*rstd*lg1.y + lb1.y);
            ov[6] = (bf16)((v1.z-m)*rstd*lg1.z + lb1.z);
            ov[7] = (bf16)((v1.w-m)*rstd*lg1.w + lb1.w);
            *(bf16x8*)&Abuf[r*AS + lane*8] = ov;
        }
    }
    __syncthreads();

    // GEMM1
    f32x4 acc[4][4];
    #pragma unroll
    for (int mt = 0; mt < 4; ++mt)
        #pragma unroll
        for (int nt = 0; nt < 4; ++nt) acc[mt][nt] = (f32x4){0.f,0.f,0.f,0.f};
    gemm_body(WqS + fragoff, &Abuf[l15*AS + grp*8], acc);

    // attF prefetch
    bf16x8 bfr[2][4];
    {
        const bf16* ab = attF + (((size_t)b*H + w) << 12);
        #pragma unroll
        for (int ks = 0; ks < 2; ++ks)
            #pragma unroll
            for (int n4 = 0; n4 < 4; ++n4)
                bfr[ks][n4] = *(const bf16x8*)&ab[(n4*2 + ks)*512 + lane*8];
    }

    // softmax (in-register, per head)
    {
        float bqv[4];
        #pragma unroll
        for (int nt = 0; nt < 4; ++nt) bqv[nt] = bq[wb + nt*16 + l15];
        #pragma unroll
        for (int mt = 0; mt < 4; ++mt)
            #pragma unroll
            for (int r = 0; r < 4; ++r){
                float v0 = acc[mt][0][r] + bqv[0];
                float v1 = acc[mt][1][r] + bqv[1];
                float v2 = acc[mt][2][r] + bqv[2];
                float v3 = acc[mt][3][r] + bqv[3];
                float mx = fmaxf(fmaxf(v0,v1), fmaxf(v2,v3));
                #pragma unroll
                for (int o = 1; o < 16; o <<= 1) mx = fmaxf(mx, __shfl_xor(mx, o));
                float e0 = __expf(v0-mx), e1 = __expf(v1-mx), e2 = __expf(v2-mx), e3 = __expf(v3-mx);
                float sden = e0+e1+e2+e3;
                #pragma unroll
                for (int o = 1; o < 16; o <<= 1) sden += __shfl_xor(sden, o);
                float inv = 1.f/sden;
                acc[mt][0][r] = e0*inv; acc[mt][1][r] = e1*inv;
                acc[mt][2][r] = e2*inv; acc[mt][3][r] = e3*inv;
            }
    }
    __syncthreads();   // all GEMM1 reads of Abuf done before overwrite

    // q -> Abuf (wave-local), fence
    #pragma unroll
    for (int mt = 0; mt < 4; ++mt)
        #pragma unroll
        for (int nt = 0; nt < 4; ++nt)
            #pragma unroll
            for (int r = 0; r < 4; ++r)
                Abuf[(mt*16 + grp*4 + r)*AS + wb + nt*16 + l15] = (bf16)acc[mt][nt][r];
    asm volatile("s_waitcnt lgkmcnt(0)" ::: "memory");
    __builtin_amdgcn_sched_barrier(0);

    // y = q @ att
    #pragma unroll
    for (int mt = 0; mt < 4; ++mt)
        #pragma unroll
        for (int nt = 0; nt < 4; ++nt) acc[mt][nt] = (f32x4){0.f,0.f,0.f,0.f};
    #pragma unroll
    for (int ks = 0; ks < 2; ++ks){
        bf16x8 qa[4];
        #pragma unroll
        for (int mt = 0; mt < 4; ++mt)
            qa[mt] = *(const bf16x8*)&Abuf[(mt*16 + l15)*AS + wb + ks*32 + grp*8];
        #pragma unroll
        for (int n4 = 0; n4 < 4; ++n4)
            #pragma unroll
            for (int mt = 0; mt < 4; ++mt)
                acc[mt][n4] = __builtin_amdgcn_mfma_f32_16x16x32_bf16(qa[mt], bfr[ks][n4], acc[mt][n4], 0, 0, 0);
    }

    // LN(y) stats
    #pragma unroll
    for (int mt = 0; mt < 4; ++mt)
        #pragma unroll
        for (int r = 0; r < 4; ++r){
            float s = 0.f, q2 = 0.f;
            #pragma unroll
            for (int nt = 0; nt < 4; ++nt){ float v = acc[mt][nt][r]; s += v; q2 += v*v; }
            #pragma unroll
            for (int o = 1; o < 16; o <<= 1){ s += __shfl_xor(s, o); q2 += __shfl_xor(q2, o); }
            if (l15 == 0){ st_s[mt*16 + grp*4 + r][w] = s; st_q[mt*16 + grp*4 + r][w] = q2; }
        }
    __syncthreads();

    // stylize + silu -> Abuf (wave-local cols)
    {
        float sgv[4], sbv[4], sscv[4], sshv[4];
        #pragma unroll
        for (int nt = 0; nt < 4; ++nt){
            int col = wb + nt*16 + l15;
            sgv[nt] = sg[col]; sbv[nt] = sb[col];
            sscv[nt] = ssb[b*1024 + col]; sshv[nt] = ssb[b*1024 + 512 + col];
        }
        #pragma unroll
        for (int mt = 0; mt < 4; ++mt)
            #pragma unroll
            for (int r = 0; r < 4; ++r){
                int row = mt*16 + grp*4 + r;
                float4 s0 = *(const float4*)&st_s[row][0];
                float4 s1 = *(const float4*)&st_s[row][4];
                float4 q0 = *(const float4*)&st_q[row][0];
                float4 q1 = *(const float4*)&st_q[row][4];
                float m = (s0.x+s0.y+s0.z+s0.w + s1.x+s1.y+s1.z+s1.w)*(1.f/D);
                float var = (q0.x+q0.y+q0.z+q0.w + q1.x+q1.y+q1.z+q1.w)*(1.f/D) - m*m;
                float rstd = rsqrtf(var + 1e-5f);
                #pragma unroll
                for (int nt = 0; nt < 4; ++nt){
                    float yn = (acc[mt][nt][r] - m)*rstd*sgv[nt] + sbv[nt];
                    float h2 = yn*(1.f + sscv[nt]) + sshv[nt];
                    Abuf[row*AS + wb + nt*16 + l15] = (bf16)(h2 * sigmoidf_(h2));
                }
            }
    }
    // wave-local flush: wave w owns kk = 2w, 2w+1 (cols 64w..64w+63 == its stylize region)
    asm volatile("s_waitcnt lgkmcnt(0)" ::: "memory");
    __builtin_amdgcn_sched_barrier(0);
    bf16* hout = hS + (size_t)blockIdx.x*HS_RB;
    #pragma unroll
    for (int kk2 = 0; kk2 < 2; ++kk2){
        int kk = 2*w + kk2;
        #pragma unroll
        for (int mt = 0; mt < 4; ++mt){
            bf16x8 v = *(const bf16x8*)&Abuf[(mt*16 + l15)*AS + kk*32 + grp*8];
            *(bf16x8*)&hout[(size_t)kk*2048 + mt*512 + lane*8] = v;
        }
    }
}

// ======== k_g2: GEMM2 (all-global operands, barrier-free) + residual epilogue ========
__global__ __launch_bounds__(512, 4) void k_g2(
    const float* __restrict__ x, const bf16* __restrict__ hS,
    const bf16* __restrict__ oWS, const float* __restrict__ ob,
    float* __restrict__ out){
    __shared__ __align__(16) float scr[16*516];     // 33 KB
    const int t = threadIdx.x, w = t >> 6, lane = t & 63;
    const int l15 = lane & 15, grp = lane >> 4;
    const long g0 = (long)blockIdx.x * MR;
    const int wb = w * 64;
    const size_t fragoff = (size_t)w*2048 + (size_t)l15*32 + (size_t)grp*8;

    f32x4 acc[4][4];
    #pragma unroll
    for (int mt = 0; mt < 4; ++mt)
        #pragma unroll
        for (int nt = 0; nt < 4; ++nt) acc[mt][nt] = (f32x4){0.f,0.f,0.f,0.f};
    gemm_gg(oWS + fragoff, hS + (size_t)blockIdx.x*HS_RB + lane*8, acc);

    // epilogue: 4 passes of 16 rows through scr -> coalesced (acc + ob + x) stores
    #pragma unroll
    for (int mt = 0; mt < 4; ++mt){
        __syncthreads();    // scr free (pass 0: harmless; later: prior reads done)
        #pragma unroll
        for (int nt = 0; nt < 4; ++nt)
            #pragma unroll
            for (int r = 0; r < 4; ++r)
                scr[(grp*4 + r)*516 + wb + nt*16 + l15] = acc[mt][nt][r];
        __syncthreads();
        #pragma unroll
        for (int i = 0; i < 4; ++i){
            int c = i*512 + t;
            int row = c >> 7, col4 = (c & 127) << 2;
            float4 v  = *(const float4*)&scr[row*516 + col4];
            size_t gi = (size_t)(g0 + mt*16 + row)*D + col4;
            float4 xb = *(const float4*)&x[gi];
            float4 o4 = *(const float4*)&ob[col4];
            float4 r4 = {v.x+o4.x+xb.x, v.y+o4.y+xb.y, v.z+o4.z+xb.z, v.w+o4.w+xb.w};
            *(float4*)&out[gi] = r4;
        }
    }
}

// ======== k_main fallback (r15-exact) for small workspace ========
__global__ __launch_bounds__(512, 4) void k_main(
    const float* __restrict__ x, const bf16* __restrict__ WqS, const float* __restrict__ bq,
    const float* __restrict__ lg, const float* __restrict__ lb,
    const bf16* __restrict__ attF, const float* __restrict__ ssb,
    const float* __restrict__ sg, const float* __restrict__ sb,
    const bf16* __restrict__ oWS, const float* __restrict__ ob,
    float* __restrict__ out){
    __shared__ __align__(16) bf16 Abuf[MR*AS];
    __shared__ float st_s[MR][8];
    __shared__ float st_q[MR][8];
    const int t = threadIdx.x, w = t >> 6, lane = t & 63;
    const int l15 = lane & 15, grp = lane >> 4;
    const long g0 = (long)blockIdx.x * MR;
    const int b = (int)(g0 / T);
    const int wb = w * 64;
    const size_t fragoff = (size_t)w*2048 + (size_t)l15*32 + (size_t)grp*8;
    {
        float4 lg0 = *(const float4*)&lg[lane*8], lg1 = *(const float4*)&lg[lane*8+4];
        float4 lb0 = *(const float4*)&lb[lane*8], lb1 = *(const float4*)&lb[lane*8+4];
        #pragma unroll 2
        for (int rr = 0; rr < 8; ++rr){
            int r = w*8 + rr;
            const float* xp = &x[(size_t)(g0 + r)*D + lane*8];
            float4 v0 = *(const float4*)xp, v1 = *(const float4*)(xp+4);
            float s  = v0.x+v0.y+v0.z+v0.w + v1.x+v1.y+v1.z+v1.w;
            float sq = v0.x*v0.x+v0.y*v0.y+v0.z*v0.z+v0.w*v0.w
                     + v1.x*v1.x+v1.y*v1.y+v1.z*v1.z+v1.w*v1.w;
            #pragma unroll
            for (int o = 32; o; o >>= 1){ s += __shfl_xor(s,o); sq += __shfl_xor(sq,o); }
            float m = s*(1.f/D), var = sq*(1.f/D) - m*m, rstd = rsqrtf(var + 1e-5f);
            bf16x8 ov;
            ov[0] = (bf16)((v0.x-m)*rstd*lg0.x + lb0.x);
            ov[1] = (bf16)((v0.y-m)*rstd*lg0.y + lb0.y);
            ov[2] = (bf16)((v0.z-m)*rstd*lg0.z + lb0.z);
            ov[3] = (bf16)((v0.w-m)*rstd*lg0.w + lb0.w);
            ov[4] = (bf16)((v1.x-m)*rstd*lg1.x + lb1.x);
            ov[5] = (bf16)((v1.y-m)*rstd*lg1.y + lb1.y);
            ov[6] = (bf16)((v1.z-m)*rstd*lg1.z + lb1.z);
            ov[7] = (bf16)((v1.w-m)*rstd*lg1.w + lb1.w);
            *(bf16x8*)&Abuf[r*AS + lane*8] = ov;
        }
    }
    __syncthreads();
    f32x4 acc[4][4];
    #pragma unroll
    for (int mt = 0; mt < 4; ++mt)
        #pragma unroll
        for (int nt = 0; nt < 4; ++nt) acc[mt][nt] = (f32x4){0.f,0.f,0.f,0.f};
    gemm_body(WqS + fragoff, &Abuf[l15*AS + grp*8], acc);
    bf16x8 bfr[2][4];
    {
        const bf16* ab = attF + (((size_t)b*H + w) << 12);
        #pragma unroll
        for (int ks = 0; ks < 2; ++ks)
            #pragma unroll
            for (int n4 = 0; n4 < 4; ++n4)
                bfr[ks][n4] = *(const bf16x8*)&ab[(n4*2 + ks)*512 + lane*8];
    }
    {
        float bqv[4];
        #pragma unroll
        for (int nt = 0; nt < 4; ++nt) bqv[nt] = bq[wb + nt*16 + l15];
        #pragma unroll
        for (int mt = 0; mt < 4; ++mt)
            #pragma unroll
            for (int r = 0; r < 4; ++r){
                float v0 = acc[mt][0][r] + bqv[0];
                float v1 = acc[mt][1][r] + bqv[1];
                float v2 = acc[mt][2][r] + bqv[2];
                float v3 = acc[mt][3][r] + bqv[3];
                float mx = fmaxf(fmaxf(v0,v1), fmaxf(v2,v3));
                #pragma unroll
                for (int o = 1; o < 16; o <<= 1) mx = fmaxf(mx, __shfl_xor(mx, o));
                float e0 = __expf(v0-mx), e1 = __expf(v1-mx), e2 = __expf(v2-mx), e3 = __expf(v3-mx);
                float sden = e0+e1+e2+e3;
                #pragma unroll
                for (int o = 1; o < 16; o <<= 1) sden += __shfl_xor(sden, o);
                float inv = 1.f/sden;
                acc[mt][0][r] = e0*inv; acc[mt][1][r] = e1*inv;
                acc[mt][2][r] = e2*inv; acc[mt][3][r] = e3*inv;
            }
    }
    __syncthreads();
    #pragma unroll
    for (int mt = 0; mt < 4; ++mt)
        #pragma unroll
        for (int nt = 0; nt < 4; ++nt)
            #pragma unroll
            for (int r = 0; r < 4; ++r)
                Abuf[(mt*16 + grp*4 + r)*AS + wb + nt*16 + l15] = (bf16)acc[mt][nt][r];
    asm volatile("s_waitcnt lgkmcnt(0)" ::: "memory");
    __builtin_amdgcn_sched_barrier(0);
    #pragma unroll
    for (int mt = 0; mt < 4; ++mt)
        #pragma unroll
        for (int nt = 0; nt < 4; ++nt) acc[mt][nt] = (f32x4){0.f,0.f,0.f,0.f};
    #pragma unroll
    for (int ks = 0; ks < 2; ++ks){
        bf16x8 qa[4];
        #pragma unroll
        for (int mt = 0; mt < 4; ++mt)
            qa[mt] = *(const bf16x8*)&Abuf[(mt*16 + l15)*AS + wb + ks*32 + grp*8];
        #pragma unroll
        for (int n4 = 0; n4 < 4; ++n4)
            #pragma unroll
            for (int mt = 0; mt < 4; ++mt)
                acc[mt][n4] = __builtin_amdgcn_mfma_f32_16x16x32_bf16(qa[mt], bfr[ks][n4], acc[mt][n4], 0, 0, 0);
    }
    #pragma unroll
    for (int mt = 0; mt < 4; ++mt)
        #pragma unroll
        for (int r = 0; r < 4; ++r){
            float s = 0.f, q2 = 0.f;
            #pragma unroll
            for (int nt = 0; nt < 4; ++nt){ float v = acc[mt][nt][r]; s += v; q2 += v*v; }
            #pragma unroll
            for (int o = 1; o < 16; o <<= 1){ s += __shfl_xor(s, o); q2 += __shfl_xor(q2, o); }
            if (l15 == 0){ st_s[mt*16 + grp*4 + r][w] = s; st_q[mt*16 + grp*4 + r][w] = q2; }
        }
    __syncthreads();
    {
        float sgv[4], sbv[4], sscv[4], sshv[4];
        #pragma unroll
        for (int nt = 0; nt < 4; ++nt){
            int col = wb + nt*16 + l15;
            sgv[nt] = sg[col]; sbv[nt] = sb[col];
            sscv[nt] = ssb[b*1024 + col]; sshv[nt] = ssb[b*1024 + 512 + col];
        }
        #pragma unroll
        for (int mt = 0; mt < 4; ++mt)
            #pragma unroll
            for (int r = 0; r < 4; ++r){
                int row = mt*16 + grp*4 + r;
                float4 s0 = *(const float4*)&st_s[row][0];
                float4 s1 = *(const float4*)&st_s[row][4];
                float4 q0 = *(const float4*)&st_q[row][0];
                float4 q1 = *(const float4*)&st_q[row][4];
                float m = (s0.x+s0.y+s0.z+s0.w + s1.x+s1.y+s1.z+s1.w)*(1.f/D);
                float var = (q0.x+q0.y+q0.z+q0.w + q1.x+q1.y+q1.z+q1.w)*(1.f/D) - m*m;
                float rstd = rsqrtf(var + 1e-5f);
                #pragma unroll
                for (int nt = 0; nt < 4; ++nt){
                    float yn = (acc[mt][nt][r] - m)*rstd*sgv[nt] + sbv[nt];
                    float h2 = yn*(1.f + sscv[nt]) + sshv[nt];
                    Abuf[row*AS + wb + nt*16 + l15] = (bf16)(h2 * sigmoidf_(h2));
                }
            }
    }
    __syncthreads();
    #pragma unroll
    for (int mt = 0; mt < 4; ++mt)
        #pragma unroll
        for (int nt = 0; nt < 4; ++nt) acc[mt][nt] = (f32x4){0.f,0.f,0.f,0.f};
    gemm_body(oWS + fragoff, &Abuf[l15*AS + grp*8], acc);
    float* scr = (float*)Abuf;
    #pragma unroll
    for (int half = 0; half < 2; ++half){
        __syncthreads();
        #pragma unroll
        for (int mt2 = 0; mt2 < 2; ++mt2){
            int mt = half*2 + mt2;
            #pragma unroll
            for (int nt = 0; nt < 4; ++nt)
                #pragma unroll
                for (int r = 0; r < 4; ++r)
                    scr[(mt2*16 + grp*4 + r)*516 + wb + nt*16 + l15] = acc[mt][nt][r];
        }
        __syncthreads();
        #pragma unroll 2
        for (int i = 0; i < 8; ++i){
            int c = i*512 + t;
            int row = c >> 7, col4 = (c & 127) << 2;
            float4 v  = *(const float4*)&scr[row*516 + col4];
            size_t gi = (size_t)(g0 + half*32 + row)*D + col4;
            float4 xb = *(const float4*)&x[gi];
            float4 o4 = *(const float4*)&ob[col4];
            float4 r4 = {v.x+o4.x+xb.x, v.y+o4.y+xb.y, v.z+o4.z+xb.z, v.w+o4.w+xb.w};
            *(float4*)&out[gi] = r4;
        }
    }
}

extern "C" void kernel_launch(void* const* d_in, const int* in_sizes, int n_in,
                              void* d_out, int out_size, void* d_ws, size_t ws_size,
                              hipStream_t stream){
    const float* x     = (const float*)d_in[0];
    const float* xf    = (const float*)d_in[1];
    const float* emb   = (const float*)d_in[2];
    const float* Wq    = (const float*)d_in[3];
    const float* bq    = (const float*)d_in[4];
    const float* Wk    = (const float*)d_in[5];
    const float* bk    = (const float*)d_in[6];
    const float* Wv    = (const float*)d_in[7];
    const float* bv    = (const float*)d_in[8];
    const float* ln_g  = (const float*)d_in[9];
    const float* ln_b  = (const float*)d_in[10];
    const float* tln_g = (const float*)d_in[11];
    const float* tln_b = (const float*)d_in[12];
    const float* emb_W = (const float*)d_in[13];
    const float* emb_b = (const float*)d_in[14];
    const float* sn_g  = (const float*)d_in[15];
    const float* sn_b  = (const float*)d_in[16];
    const float* out_W = (const float*)d_in[17];
    const float* out_b = (const float*)d_in[18];
    float* out = (float*)d_out;

    // workspace carve
    float* ssb  = (float*)d_ws;                          // B*1024 f32
    bf16*  kbuf = (bf16*)(ssb + B*1024);                 // B*NN*D bf16
    bf16*  vbuf = kbuf + (size_t)B*NN*D;                 // B*NN*D bf16
    bf16*  attF = vbuf + (size_t)B*NN*D;                 // B*H*DH*DH bf16
    bf16*  wqS  = attF + (size_t)B*H*DH*DH;              // D*D bf16
    bf16*  owS  = wqS  + (size_t)D*D;                    // D*D bf16
    bf16*  hS   = owS  + (size_t)D*D;                    // B*T*D bf16 (split path only)
    const size_t base_bytes = (size_t)(4096*4) + 4u*1024*1024 + 256*1024 + 1024*1024;
    const size_t need_split = base_bytes + (size_t)B*T*D*2;

    k_prep_all<<<dim3(704), dim3(256), 0, stream>>>(xf, Wk, bk, Wv, bv, tln_g, tln_b, kbuf, vbuf,
                                                    Wq, out_W, wqS, owS,
                                                    emb, emb_W, emb_b, ssb);
    k_att     <<<dim3(H, B), dim3(512), 0, stream>>>(kbuf, vbuf, attF);
    if (ws_size >= need_split){
        k_g1<<<dim3(B*T/MR), dim3(512), 0, stream>>>(x, wqS, bq, ln_g, ln_b, attF, ssb,
                                                     sn_g, sn_b, hS);
        k_g2<<<dim3(B*T/MR), dim3(512), 0, stream>>>(x, hS, owS, out_b, out);
    } else {
        k_main<<<dim3(B*T/MR), dim3(512), 0, stream>>>(x, wqS, bq, ln_g, ln_b, attF, ssb,
                                                       sn_g, sn_b, owS, out_b, out);
    }
}

// Round 17
// 141.344 us; speedup vs baseline: 1.1548x; 1.1548x over previous
//
#include <hip/hip_runtime.h>
#include <math.h>
#include <stdint.h>

#define B 4
#define T 8192
#define D 512
#define NN 256
#define L 768
#define TE 2048
#define H 8
#define DH 64
#define MR 64
#define AS 520          // Abuf row stride (bf16 elems)
#define SLICE 16384     // elems per 32-K staged slice (512 cols * 32 k)
#define XST 776         // k_kv LDS row stride (bf16), 16B-aligned

typedef __bf16 bf16;
typedef bf16  bf16x8 __attribute__((ext_vector_type(8)));
typedef float f32x4  __attribute__((ext_vector_type(4)));

__device__ __forceinline__ float sigmoidf_(float x){ return 1.0f/(1.0f+__expf(-x)); }

// ======== k_prep_all: weight re-layouts + ss ========
// [0,128): Wq/oW (512x512) -> staged [kk][col][k']
// [128,320): Wk/Wv (768x512) -> staged (96 tiles each)
// [320,384): ss = silu(emb) @ emb_W + emb_b
__global__ __launch_bounds__(256) void k_prep_all(
    const float* __restrict__ Wq, const float* __restrict__ oW,
    bf16* __restrict__ wqS, bf16* __restrict__ owS,
    const float* __restrict__ Wk, const float* __restrict__ Wv,
    bf16* __restrict__ wkS, bf16* __restrict__ wvS,
    const float* __restrict__ emb, const float* __restrict__ emb_W,
    const float* __restrict__ emb_b, float* __restrict__ ss){
    __shared__ __align__(16) char smem[36864];
    const int bid = blockIdx.x, t = threadIdx.x;
    if (bid < 320){
        const float* W; bf16* Wst; int k0, n0, kkbase;
        if (bid < 128){
            int lb2 = bid;
            W = (lb2 < 64) ? Wq : oW;
            Wst = (lb2 < 64) ? wqS : owS;
            int lb = lb2 & 63;
            k0 = (lb & 7)*64; n0 = (lb >> 3)*64;
            kkbase = (lb & 7)*2;
        } else {
            int lb2 = bid - 128;
            W = (lb2 < 96) ? Wk : Wv;
            Wst = (lb2 < 96) ? wkS : wvS;
            int lb = (lb2 < 96) ? lb2 : lb2 - 96;
            k0 = (lb % 12)*64; n0 = (lb / 12)*64;
            kkbase = (lb % 12)*2;
        }
        float (*tile)[65] = (float(*)[65])smem;
        int c = t & 63, r4 = t >> 6;
        #pragma unroll
        for (int p = 0; p < 16; ++p){ int r = p*4 + r4; tile[r][c] = W[(size_t)(k0+r)*D + n0 + c]; }
        __syncthreads();
        int oct = t >> 6, col = t & 63;
        #pragma unroll
        for (int half = 0; half < 2; ++half){
            int kk = kkbase + half;
            bf16x8 ov;
            #pragma unroll
            for (int j = 0; j < 8; ++j) ov[j] = (bf16)tile[half*32 + oct*8 + j][col];
            *(bf16x8*)&Wst[(size_t)kk*SLICE + (n0+col)*32 + oct*8] = ov;
        }
    } else {
        float (*semb)[TE] = (float(*)[TE])smem;                 // 32 KB
        float (*red)[64]  = (float(*)[64])(smem + 4*TE*4);      // 4 KB
        int c = bid - 320;
        for (int i = t; i < TE; i += 256)
            #pragma unroll
            for (int b = 0; b < B; ++b){ float e = emb[b*TE + i]; semb[b][i] = e * sigmoidf_(e); }
        __syncthreads();
        int o = t & 15, p = t >> 4;
        int j = c*16 + o;
        float acc[B] = {0.f,0.f,0.f,0.f};
        for (int i = 0; i < 128; ++i){
            int e = p*128 + i;
            float wv = emb_W[(size_t)e*1024 + j];
            #pragma unroll
            for (int b = 0; b < B; ++b) acc[b] += semb[b][e] * wv;
        }
        #pragma unroll
        for (int b = 0; b < B; ++b) red[p][b*16 + o] = acc[b];
        __syncthreads();
        if (t < 64){
            int b = t >> 4, o2 = t & 15;
            int j2 = c*16 + o2;
            float s = 0.f;
            #pragma unroll
            for (int pp = 0; pp < 16; ++pp) s += red[pp][b*16 + o2];
            ss[b*1024 + j2] = s + emb_b[j2];
        }
    }
}

// ======== k_kv: LN(xf) + MFMA k/v projection (16 rows/block, 64 blocks) ========
__global__ __launch_bounds__(512) void k_kv(
    const float* __restrict__ xf, const bf16* __restrict__ wkS, const bf16* __restrict__ wvS,
    const float* __restrict__ bk, const float* __restrict__ bv,
    const float* __restrict__ tg, const float* __restrict__ tb,
    bf16* __restrict__ kbuf, bf16* __restrict__ vbuf){
    __shared__ __align__(16) bf16 xfn[16*XST];   // 24.25 KB
    const int t = threadIdx.x, w = t >> 6, lane = t & 63;
    const int l15 = lane & 15, grp = lane >> 4;
    const int g0 = blockIdx.x * 16;
    const int wb = w * 64;

    // LN: wave w handles rows 2w, 2w+1 (768 elems, 12/lane, f32 math -> bf16 LDS)
    #pragma unroll
    for (int rr = 0; rr < 2; ++rr){
        int r = w*2 + rr, g = g0 + r;
        float vals[12];
        float s = 0.f, sq = 0.f;
        #pragma unroll
        for (int i = 0; i < 12; ++i){ float v = xf[(size_t)g*L + lane*12 + i]; vals[i] = v; s += v; sq += v*v; }
        #pragma unroll
        for (int o = 32; o; o >>= 1){ s += __shfl_xor(s, o); sq += __shfl_xor(sq, o); }
        float m = s / L; float var = sq / L - m*m;
        float rstd = rsqrtf(var + 1e-5f);
        #pragma unroll
        for (int i = 0; i < 12; ++i){
            int l = lane*12 + i;
            xfn[r*XST + l] = (bf16)((vals[i]-m)*rstd*tg[l] + tb[l]);
        }
    }
    __syncthreads();

    // MFMA: acc_k/acc_v [nt] over K=768 (24 slices); A row = l15, B col = wb+nt*16+l15
    f32x4 ak[4], av[4];
    #pragma unroll
    for (int nt = 0; nt < 4; ++nt){ ak[nt] = (f32x4){0.f,0.f,0.f,0.f}; av[nt] = (f32x4){0.f,0.f,0.f,0.f}; }
    const bf16* wkf = wkS + (size_t)wb*32 + (size_t)l15*32 + (size_t)grp*8;
    const bf16* wvf = wvS + (size_t)wb*32 + (size_t)l15*32 + (size_t)grp*8;
    for (int kk = 0; kk < 24; ++kk){
        bf16x8 aa = *(const bf16x8*)&xfn[l15*XST + kk*32 + grp*8];
        #pragma unroll
        for (int nt = 0; nt < 4; ++nt){
            bf16x8 bb = *(const bf16x8*)&wkf[(size_t)kk*SLICE + nt*512];
            ak[nt] = __builtin_amdgcn_mfma_f32_16x16x32_bf16(aa, bb, ak[nt], 0, 0, 0);
        }
        #pragma unroll
        for (int nt = 0; nt < 4; ++nt){
            bf16x8 bb = *(const bf16x8*)&wvf[(size_t)kk*SLICE + nt*512];
            av[nt] = __builtin_amdgcn_mfma_f32_16x16x32_bf16(aa, bb, av[nt], 0, 0, 0);
        }
    }
    // store: row = grp*4+r, col = wb + nt*16 + l15
    #pragma unroll
    for (int nt = 0; nt < 4; ++nt){
        int col = wb + nt*16 + l15;
        float bkc = bk[col], bvc = bv[col];
        #pragma unroll
        for (int r = 0; r < 4; ++r){
            size_t gi = (size_t)(g0 + grp*4 + r)*D + col;
            kbuf[gi] = (bf16)(ak[nt][r] + bkc);
            vbuf[gi] = (bf16)(av[nt][r] + bvc);
        }
    }
}

// ======== k_att: attn state, 512 threads (r15 exact) ========
__global__ __launch_bounds__(512) void k_att(const bf16* __restrict__ kbuf,
                                             const bf16* __restrict__ vbuf,
                                             bf16* __restrict__ attF){
    __shared__ float kh[NN*DH];
    __shared__ float vh[NN*DH];
    __shared__ float pm[8][DH], ps[8][DH];
    int t = threadIdx.x, h = blockIdx.x, b = blockIdx.y;
    for (int k = 0; k < NN*DH/512; ++k){
        int m = k*512 + t;
        int n = m >> 6, dl = m & 63;
        size_t src = (size_t)(b*NN + n)*D + h*DH + dl;
        kh[m] = (float)kbuf[src]; vh[m] = (float)vbuf[src];
    }
    __syncthreads();
    int d = t & 63, c = t >> 6;
    float mx = -1e30f;
    for (int n = c*32; n < c*32+32; ++n) mx = fmaxf(mx, kh[n*DH + d]);
    pm[c][d] = mx;
    __syncthreads();
    mx = pm[0][d];
    #pragma unroll
    for (int cc = 1; cc < 8; ++cc) mx = fmaxf(mx, pm[cc][d]);
    float s = 0.f;
    for (int n = c*32; n < c*32+32; ++n){ float e = __expf(kh[n*DH + d] - mx); kh[n*DH + d] = e; s += e; }
    ps[c][d] = s;
    __syncthreads();
    float sden = ps[0][d];
    #pragma unroll
    for (int cc = 1; cc < 8; ++cc) sden += ps[cc][d];
    float inv = 1.f/sden;
    for (int n = c*32; n < c*32+32; ++n) kh[n*DH + d] *= inv;
    __syncthreads();
    int dl = t >> 3, dd0 = (t & 7)*8;
    float acc[8];
    #pragma unroll
    for (int i = 0; i < 8; ++i) acc[i] = 0.f;
    for (int n = 0; n < NN; ++n){
        float vv = vh[n*DH + dl];
        #pragma unroll
        for (int i = 0; i < 8; ++i) acc[i] += kh[n*DH + dd0 + i] * vv;
    }
    size_t hbase = ((size_t)(b*H + h)) << 12;
    int f  = (dl >> 4)*2 + (dd0 >> 5);
    int ln = ((dd0 >> 3) & 3)*16 + (dl & 15);
    bf16x8 ov;
    #pragma unroll
    for (int j = 0; j < 8; ++j) ov[j] = (bf16)acc[j];
    *(bf16x8*)&attF[hbase + f*512 + ln*8] = ov;
}

// ======== rolled, register-double-buffered GEMM over K=512 (+T5 setprio) — r10/r15 exact ========
__device__ __forceinline__ void gemm_body(const bf16* __restrict__ wfrag,
                                          const bf16* __restrict__ afrag,
                                          f32x4 (&acc)[4][4]){
    bf16x8 b0[4], b1[4];
    #pragma unroll
    for (int nt = 0; nt < 4; ++nt) b0[nt] = *(const bf16x8*)&wfrag[nt*512];
    #pragma unroll
    for (int nt = 0; nt < 4; ++nt) b1[nt] = *(const bf16x8*)&wfrag[SLICE + nt*512];
    const bf16* wp = wfrag + 2*(size_t)SLICE;
    const bf16* ap = afrag;
    __builtin_amdgcn_s_setprio(1);
    for (int kk = 0; kk < 14; kk += 2){
        bf16x8 aa[4];
        #pragma unroll
        for (int mt = 0; mt < 4; ++mt) aa[mt] = *(const bf16x8*)&ap[mt*16*AS];
        #pragma unroll
        for (int nt = 0; nt < 4; ++nt)
            #pragma unroll
            for (int mt = 0; mt < 4; ++mt)
                acc[mt][nt] = __builtin_amdgcn_mfma_f32_16x16x32_bf16(aa[mt], b0[nt], acc[mt][nt], 0, 0, 0);
        #pragma unroll
        for (int nt = 0; nt < 4; ++nt) b0[nt] = *(const bf16x8*)&wp[nt*512];
        #pragma unroll
        for (int mt = 0; mt < 4; ++mt) aa[mt] = *(const bf16x8*)&ap[mt*16*AS + 32];
        #pragma unroll
        for (int nt = 0; nt < 4; ++nt)
            #pragma unroll
            for (int mt = 0; mt < 4; ++mt)
                acc[mt][nt] = __builtin_amdgcn_mfma_f32_16x16x32_bf16(aa[mt], b1[nt], acc[mt][nt], 0, 0, 0);
        #pragma unroll
        for (int nt = 0; nt < 4; ++nt) b1[nt] = *(const bf16x8*)&wp[SLICE + nt*512];
        wp += 2*(size_t)SLICE; ap += 64;
    }
    {
        bf16x8 aa[4];
        #pragma unroll
        for (int mt = 0; mt < 4; ++mt) aa[mt] = *(const bf16x8*)&ap[mt*16*AS];
        #pragma unroll
        for (int nt = 0; nt < 4; ++nt)
            #pragma unroll
            for (int mt = 0; mt < 4; ++mt)
                acc[mt][nt] = __builtin_amdgcn_mfma_f32_16x16x32_bf16(aa[mt], b0[nt], acc[mt][nt], 0, 0, 0);
        #pragma unroll
        for (int mt = 0; mt < 4; ++mt) aa[mt] = *(const bf16x8*)&ap[mt*16*AS + 32];
        #pragma unroll
        for (int nt = 0; nt < 4; ++nt)
            #pragma unroll
            for (int mt = 0; mt < 4; ++mt)
                acc[mt][nt] = __builtin_amdgcn_mfma_f32_16x16x32_bf16(aa[mt], b1[nt], acc[mt][nt], 0, 0, 0);
    }
    __builtin_amdgcn_s_setprio(0);
}

// ======== main fused kernel (r15 exact): 64 rows/block, 8 waves, 2 blocks/CU ========
__global__ __launch_bounds__(512, 4) void k_main(
    const float* __restrict__ x, const bf16* __restrict__ WqS, const float* __restrict__ bq,
    const float* __restrict__ lg, const float* __restrict__ lb,
    const bf16* __restrict__ attF, const float* __restrict__ ssb,
    const float* __restrict__ sg, const float* __restrict__ sb,
    const bf16* __restrict__ oWS, const float* __restrict__ ob,
    float* __restrict__ out){
    __shared__ __align__(16) bf16 Abuf[MR*AS];
    __shared__ float st_s[MR][8];
    __shared__ float st_q[MR][8];
    const int t = threadIdx.x, w = t >> 6, lane = t & 63;
    const int l15 = lane & 15, grp = lane >> 4;
    const long g0 = (long)blockIdx.x * MR;
    const int b = (int)(g0 / T);
    const int wb = w * 64;
    const size_t fragoff = (size_t)w*2048 + (size_t)l15*32 + (size_t)grp*8;

    {
        float4 lg0 = *(const float4*)&lg[lane*8], lg1 = *(const float4*)&lg[lane*8+4];
        float4 lb0 = *(const float4*)&lb[lane*8], lb1 = *(const float4*)&lb[lane*8+4];
        #pragma unroll 2
        for (int rr = 0; rr < 8; ++rr){
            int r = w*8 + rr;
            const float* xp = &x[(size_t)(g0 + r)*D + lane*8];
            float4 v0 = *(const float4*)xp, v1 = *(const float4*)(xp+4);
            float s  = v0.x+v0.y+v0.z+v0.w + v1.x+v1.y+v1.z+v1.w;
            float sq = v0.x*v0.x+v0.y*v0.y+v0.z*v0.z+v0.w*v0.w
                     + v1.x*v1.x+v1.y*v1.y+v1.z*v1.z+v1.w*v1.w;
            #pragma unroll
            for (int o = 32; o; o >>= 1){ s += __shfl_xor(s,o); sq += __shfl_xor(sq,o); }
            float m = s*(1.f/D), var = sq*(1.f/D) - m*m, rstd = rsqrtf(var + 1e-5f);
            bf16x8 ov;
            ov[0] = (bf16)((v0.x-m)*rstd*lg0.x + lb0.x);
            ov[1] = (bf16)((v0.y-m)*rstd*lg0.y + lb0.y);
            ov[2] = (bf16)((v0.z-m)*rstd*lg0.z + lb0.z);
            ov[3] = (bf16)((v0.w-m)*rstd*lg0.w + lb0.w);
            ov[4] = (bf16)((v1.x-m)*rstd*lg1.x + lb1.x);
            ov[5] = (bf16)((v1.y-m)*rstd*lg1.y + lb1.y);
            ov[6] = (bf16)((v1.z-m)*rstd*lg1.z + lb1.z);
            ov[7] = (bf16)((v1.w-m)*rstd*lg1.w + lb1.w);
            *(bf16x8*)&Abuf[r*AS + lane*8] = ov;
        }
    }
    __syncthreads();

    f32x4 acc[4][4];
    #pragma unroll
    for (int mt = 0; mt < 4; ++mt)
        #pragma unroll
        for (int nt = 0; nt < 4; ++nt) acc[mt][nt] = (f32x4){0.f,0.f,0.f,0.f};
    gemm_body(WqS + fragoff, &Abuf[l15*AS + grp*8], acc);

    bf16x8 bfr[2][4];
    {
        const bf16* ab = attF + (((size_t)b*H + w) << 12);
        #pragma unroll
        for (int ks = 0; ks < 2; ++ks)
            #pragma unroll
            for (int n4 = 0; n4 < 4; ++n4)
                bfr[ks][n4] = *(const bf16x8*)&ab[(n4*2 + ks)*512 + lane*8];
    }

    {
        float bqv[4];
        #pragma unroll
        for (int nt = 0; nt < 4; ++nt) bqv[nt] = bq[wb + nt*16 + l15];
        #pragma unroll
        for (int mt = 0; mt < 4; ++mt)
            #pragma unroll
            for (int r = 0; r < 4; ++r){
                float v0 = acc[mt][0][r] + bqv[0];
                float v1 = acc[mt][1][r] + bqv[1];
                float v2 = acc[mt][2][r] + bqv[2];
                float v3 = acc[mt][3][r] + bqv[3];
                float mx = fmaxf(fmaxf(v0,v1), fmaxf(v2,v3));
                #pragma unroll
                for (int o = 1; o < 16; o <<= 1) mx = fmaxf(mx, __shfl_xor(mx, o));
                float e0 = __expf(v0-mx), e1 = __expf(v1-mx), e2 = __expf(v2-mx), e3 = __expf(v3-mx);
                float sden = e0+e1+e2+e3;
                #pragma unroll
                for (int o = 1; o < 16; o <<= 1) sden += __shfl_xor(sden, o);
                float inv = 1.f/sden;
                acc[mt][0][r] = e0*inv; acc[mt][1][r] = e1*inv;
                acc[mt][2][r] = e2*inv; acc[mt][3][r] = e3*inv;
            }
    }
    __syncthreads();

    #pragma unroll
    for (int mt = 0; mt < 4; ++mt)
        #pragma unroll
        for (int nt = 0; nt < 4; ++nt)
            #pragma unroll
            for (int r = 0; r < 4; ++r)
                Abuf[(mt*16 + grp*4 + r)*AS + wb + nt*16 + l15] = (bf16)acc[mt][nt][r];
    asm volatile("s_waitcnt lgkmcnt(0)" ::: "memory");
    __builtin_amdgcn_sched_barrier(0);

    #pragma unroll
    for (int mt = 0; mt < 4; ++mt)
        #pragma unroll
        for (int nt = 0; nt < 4; ++nt) acc[mt][nt] = (f32x4){0.f,0.f,0.f,0.f};
    #pragma unroll
    for (int ks = 0; ks < 2; ++ks){
        bf16x8 qa[4];
        #pragma unroll
        for (int mt = 0; mt < 4; ++mt)
            qa[mt] = *(const bf16x8*)&Abuf[(mt*16 + l15)*AS + wb + ks*32 + grp*8];
        #pragma unroll
        for (int n4 = 0; n4 < 4; ++n4)
            #pragma unroll
            for (int mt = 0; mt < 4; ++mt)
                acc[mt][n4] = __builtin_amdgcn_mfma_f32_16x16x32_bf16(qa[mt], bfr[ks][n4], acc[mt][n4], 0, 0, 0);
    }

    #pragma unroll
    for (int mt = 0; mt < 4; ++mt)
        #pragma unroll
        for (int r = 0; r < 4; ++r){
            float s = 0.f, q2 = 0.f;
            #pragma unroll
            for (int nt = 0; nt < 4; ++nt){ float v = acc[mt][nt][r]; s += v; q2 += v*v; }
            #pragma unroll
            for (int o = 1; o < 16; o <<= 1){ s += __shfl_xor(s, o); q2 += __shfl_xor(q2, o); }
            if (l15 == 0){ st_s[mt*16 + grp*4 + r][w] = s; st_q[mt*16 + grp*4 + r][w] = q2; }
        }
    __syncthreads();

    {
        float sgv[4], sbv[4], sscv[4], sshv[4];
        #pragma unroll
        for (int nt = 0; nt < 4; ++nt){
            int col = wb + nt*16 + l15;
            sgv[nt] = sg[col]; sbv[nt] = sb[col];
            sscv[nt] = ssb[b*1024 + col]; sshv[nt] = ssb[b*1024 + 512 + col];
        }
        #pragma unroll
        for (int mt = 0; mt < 4; ++mt)
            #pragma unroll
            for (int r = 0; r < 4; ++r){
                int row = mt*16 + grp*4 + r;
                float4 s0 = *(const float4*)&st_s[row][0];
                float4 s1 = *(const float4*)&st_s[row][4];
                float4 q0 = *(const float4*)&st_q[row][0];
                float4 q1 = *(const float4*)&st_q[row][4];
                float m = (s0.x+s0.y+s0.z+s0.w + s1.x+s1.y+s1.z+s1.w)*(1.f/D);
                float var = (q0.x+q0.y+q0.z+q0.w + q1.x+q1.y+q1.z+q1.w)*(1.f/D) - m*m;
                float rstd = rsqrtf(var + 1e-5f);
                #pragma unroll
                for (int nt = 0; nt < 4; ++nt){
                    float yn = (acc[mt][nt][r] - m)*rstd*sgv[nt] + sbv[nt];
                    float h2 = yn*(1.f + sscv[nt]) + sshv[nt];
                    Abuf[row*AS + wb + nt*16 + l15] = (bf16)(h2 * sigmoidf_(h2));
                }
            }
    }
    __syncthreads();

    #pragma unroll
    for (int mt = 0; mt < 4; ++mt)
        #pragma unroll
        for (int nt = 0; nt < 4; ++nt) acc[mt][nt] = (f32x4){0.f,0.f,0.f,0.f};
    gemm_body(oWS + fragoff, &Abuf[l15*AS + grp*8], acc);

    float* scr = (float*)Abuf;
    #pragma unroll
    for (int half = 0; half < 2; ++half){
        __syncthreads();
        #pragma unroll
        for (int mt2 = 0; mt2 < 2; ++mt2){
            int mt = half*2 + mt2;
            #pragma unroll
            for (int nt = 0; nt < 4; ++nt)
                #pragma unroll
                for (int r = 0; r < 4; ++r)
                    scr[(mt2*16 + grp*4 + r)*516 + wb + nt*16 + l15] = acc[mt][nt][r];
        }
        __syncthreads();
        #pragma unroll 2
        for (int i = 0; i < 8; ++i){
            int c = i*512 + t;
            int row = c >> 7, col4 = (c & 127) << 2;
            float4 v  = *(const float4*)&scr[row*516 + col4];
            size_t gi = (size_t)(g0 + half*32 + row)*D + col4;
            float4 xb = *(const float4*)&x[gi];
            float4 o4 = *(const float4*)&ob[col4];
            float4 r4 = {v.x+o4.x+xb.x, v.y+o4.y+xb.y, v.z+o4.z+xb.z, v.w+o4.w+xb.w};
            *(float4*)&out[gi] = r4;
        }
    }
}

extern "C" void kernel_launch(void* const* d_in, const int* in_sizes, int n_in,
                              void* d_out, int out_size, void* d_ws, size_t ws_size,
                              hipStream_t stream){
    const float* x     = (const float*)d_in[0];
    const float* xf    = (const float*)d_in[1];
    const float* emb   = (const float*)d_in[2];
    const float* Wq    = (const float*)d_in[3];
    const float* bq    = (const float*)d_in[4];
    const float* Wk    = (const float*)d_in[5];
    const float* bk    = (const float*)d_in[6];
    const float* Wv    = (const float*)d_in[7];
    const float* bv    = (const float*)d_in[8];
    const float* ln_g  = (const float*)d_in[9];
    const float* ln_b  = (const float*)d_in[10];
    const float* tln_g = (const float*)d_in[11];
    const float* tln_b = (const float*)d_in[12];
    const float* emb_W = (const float*)d_in[13];
    const float* emb_b = (const float*)d_in[14];
    const float* sn_g  = (const float*)d_in[15];
    const float* sn_b  = (const float*)d_in[16];
    const float* out_W = (const float*)d_in[17];
    const float* out_b = (const float*)d_in[18];
    float* out = (float*)d_out;

    // workspace carve (~4.9 MB; r16 proved ws_size >= 37 MB)
    float* ssb  = (float*)d_ws;                          // B*1024 f32
    bf16*  kbuf = (bf16*)(ssb + B*1024);                 // B*NN*D bf16
    bf16*  vbuf = kbuf + (size_t)B*NN*D;                 // B*NN*D bf16
    bf16*  attF = vbuf + (size_t)B*NN*D;                 // B*H*DH*DH bf16
    bf16*  wqS  = attF + (size_t)B*H*DH*DH;              // D*D bf16 (staged)
    bf16*  owS  = wqS  + (size_t)D*D;                    // D*D bf16 (staged)
    bf16*  wkS  = owS  + (size_t)D*D;                    // L*D bf16 (staged)
    bf16*  wvS  = wkS  + (size_t)L*D;                    // L*D bf16 (staged)

    k_prep_all<<<dim3(384),    dim3(256), 0, stream>>>(Wq, out_W, wqS, owS,
                                                       Wk, Wv, wkS, wvS,
                                                       emb, emb_W, emb_b, ssb);
    k_kv      <<<dim3(B*NN/16), dim3(512), 0, stream>>>(xf, wkS, wvS, bk, bv,
                                                        tln_g, tln_b, kbuf, vbuf);
    k_att     <<<dim3(H, B),    dim3(512), 0, stream>>>(kbuf, vbuf, attF);
    k_main    <<<dim3(B*T/MR),  dim3(512), 0, stream>>>(x, wqS, bq, ln_g, ln_b, attF, ssb,
                                                        sn_g, sn_b, owS, out_b, out);
}

// Round 19
// 132.838 us; speedup vs baseline: 1.2288x; 1.0640x over previous
//
#include <hip/hip_runtime.h>
#include <math.h>
#include <stdint.h>

#define B 4
#define T 8192
#define D 512
#define NN 256
#define L 768
#define TE 2048
#define H 8
#define DH 64
#define MR 64
#define AS 520          // Abuf row stride (bf16 elems)
#define SLICE 16384     // elems per 32-K staged slice (512 cols * 32 k)
#define XST 776         // k_kv LDS row stride (bf16), 16B-aligned

typedef __bf16 bf16;
typedef bf16  bf16x8 __attribute__((ext_vector_type(8)));
typedef float f32x4  __attribute__((ext_vector_type(4)));

__device__ __forceinline__ float sigmoidf_(float x){ return 1.0f/(1.0f+__expf(-x)); }

// ======== k_prepKV: Wk/Wv relayout ONLY (critical path for k_kv) ========
// 192 blocks: [0,96) Wk tiles, [96,192) Wv tiles  (768x512 -> staged [kk][col][k'])
__global__ __launch_bounds__(256) void k_prepKV(
    const float* __restrict__ Wk, const float* __restrict__ Wv,
    bf16* __restrict__ wkS, bf16* __restrict__ wvS){
    __shared__ __align__(16) float tile[64][65];
    const int bid = blockIdx.x, t = threadIdx.x;
    const float* W = (bid < 96) ? Wk : Wv;
    bf16* Wst = (bid < 96) ? wkS : wvS;
    int lb = (bid < 96) ? bid : bid - 96;
    int k0 = (lb % 12)*64, n0 = (lb / 12)*64;
    int kkbase = (lb % 12)*2;
    int c = t & 63, r4 = t >> 6;
    #pragma unroll
    for (int p = 0; p < 16; ++p){ int r = p*4 + r4; tile[r][c] = W[(size_t)(k0+r)*D + n0 + c]; }
    __syncthreads();
    int oct = t >> 6, col = t & 63;
    #pragma unroll
    for (int half = 0; half < 2; ++half){
        int kk = kkbase + half;
        bf16x8 ov;
        #pragma unroll
        for (int j = 0; j < 8; ++j) ov[j] = (bf16)tile[half*32 + oct*8 + j][col];
        *(bf16x8*)&Wst[(size_t)kk*SLICE + (n0+col)*32 + oct*8] = ov;
    }
}

// ======== k_kv: LN(xf) + MFMA k/v projection (r17 exact) ========
__global__ __launch_bounds__(512) void k_kv(
    const float* __restrict__ xf, const bf16* __restrict__ wkS, const bf16* __restrict__ wvS,
    const float* __restrict__ bk, const float* __restrict__ bv,
    const float* __restrict__ tg, const float* __restrict__ tb,
    bf16* __restrict__ kbuf, bf16* __restrict__ vbuf){
    __shared__ __align__(16) bf16 xfn[16*XST];
    const int t = threadIdx.x, w = t >> 6, lane = t & 63;
    const int l15 = lane & 15, grp = lane >> 4;
    const int g0 = blockIdx.x * 16;
    const int wb = w * 64;
    #pragma unroll
    for (int rr = 0; rr < 2; ++rr){
        int r = w*2 + rr, g = g0 + r;
        float vals[12];
        float s = 0.f, sq = 0.f;
        #pragma unroll
        for (int i = 0; i < 12; ++i){ float v = xf[(size_t)g*L + lane*12 + i]; vals[i] = v; s += v; sq += v*v; }
        #pragma unroll
        for (int o = 32; o; o >>= 1){ s += __shfl_xor(s, o); sq += __shfl_xor(sq, o); }
        float m = s / L; float var = sq / L - m*m;
        float rstd = rsqrtf(var + 1e-5f);
        #pragma unroll
        for (int i = 0; i < 12; ++i){
            int l = lane*12 + i;
            xfn[r*XST + l] = (bf16)((vals[i]-m)*rstd*tg[l] + tb[l]);
        }
    }
    __syncthreads();
    f32x4 ak[4], av[4];
    #pragma unroll
    for (int nt = 0; nt < 4; ++nt){ ak[nt] = (f32x4){0.f,0.f,0.f,0.f}; av[nt] = (f32x4){0.f,0.f,0.f,0.f}; }
    const bf16* wkf = wkS + (size_t)wb*32 + (size_t)l15*32 + (size_t)grp*8;
    const bf16* wvf = wvS + (size_t)wb*32 + (size_t)l15*32 + (size_t)grp*8;
    for (int kk = 0; kk < 24; ++kk){
        bf16x8 aa = *(const bf16x8*)&xfn[l15*XST + kk*32 + grp*8];
        #pragma unroll
        for (int nt = 0; nt < 4; ++nt){
            bf16x8 bb = *(const bf16x8*)&wkf[(size_t)kk*SLICE + nt*512];
            ak[nt] = __builtin_amdgcn_mfma_f32_16x16x32_bf16(aa, bb, ak[nt], 0, 0, 0);
        }
        #pragma unroll
        for (int nt = 0; nt < 4; ++nt){
            bf16x8 bb = *(const bf16x8*)&wvf[(size_t)kk*SLICE + nt*512];
            av[nt] = __builtin_amdgcn_mfma_f32_16x16x32_bf16(aa, bb, av[nt], 0, 0, 0);
        }
    }
    #pragma unroll
    for (int nt = 0; nt < 4; ++nt){
        int col = wb + nt*16 + l15;
        float bkc = bk[col], bvc = bv[col];
        #pragma unroll
        for (int r = 0; r < 4; ++r){
            size_t gi = (size_t)(g0 + grp*4 + r)*D + col;
            kbuf[gi] = (bf16)(ak[nt][r] + bkc);
            vbuf[gi] = (bf16)(av[nt][r] + bvc);
        }
    }
}

// ======== k_rest: [0,32) attn state | [32,160) Wq/oW relayout | [160,224) ss ========
__global__ __launch_bounds__(512) void k_rest(
    const bf16* __restrict__ kbuf, const bf16* __restrict__ vbuf, bf16* __restrict__ attF,
    const float* __restrict__ Wq, const float* __restrict__ oW,
    bf16* __restrict__ wqS, bf16* __restrict__ owS,
    const float* __restrict__ emb, const float* __restrict__ emb_W,
    const float* __restrict__ emb_b, float* __restrict__ ss){
    __shared__ __align__(16) char smem[135168];
    const int bid = blockIdx.x, t = threadIdx.x;
    if (bid < 32){
        // ---- attn state for (b,h), 512 threads
        float* kh = (float*)smem;
        float* vh = kh + NN*DH;
        float (*pm)[DH] = (float(*)[DH])(vh + NN*DH);
        float (*ps)[DH] = pm + 8;
        int h = bid & 7, b = bid >> 3;
        for (int k = 0; k < NN*DH/512; ++k){
            int m = k*512 + t;
            int n = m >> 6, dl = m & 63;
            size_t src = (size_t)(b*NN + n)*D + h*DH + dl;
            kh[m] = (float)kbuf[src]; vh[m] = (float)vbuf[src];
        }
        __syncthreads();
        int d = t & 63, c = t >> 6;
        float mx = -1e30f;
        for (int n = c*32; n < c*32+32; ++n) mx = fmaxf(mx, kh[n*DH + d]);
        pm[c][d] = mx;
        __syncthreads();
        mx = pm[0][d];
        #pragma unroll
        for (int cc = 1; cc < 8; ++cc) mx = fmaxf(mx, pm[cc][d]);
        float s = 0.f;
        for (int n = c*32; n < c*32+32; ++n){ float e = __expf(kh[n*DH + d] - mx); kh[n*DH + d] = e; s += e; }
        ps[c][d] = s;
        __syncthreads();
        float sden = ps[0][d];
        #pragma unroll
        for (int cc = 1; cc < 8; ++cc) sden += ps[cc][d];
        float inv = 1.f/sden;
        for (int n = c*32; n < c*32+32; ++n) kh[n*DH + d] *= inv;
        __syncthreads();
        int dl = t >> 3, dd0 = (t & 7)*8;
        float acc[8];
        #pragma unroll
        for (int i = 0; i < 8; ++i) acc[i] = 0.f;
        for (int n = 0; n < NN; ++n){
            float vv = vh[n*DH + dl];
            #pragma unroll
            for (int i = 0; i < 8; ++i) acc[i] += kh[n*DH + dd0 + i] * vv;
        }
        size_t hbase = ((size_t)(b*H + h)) << 12;
        int f  = (dl >> 4)*2 + (dd0 >> 5);
        int ln = ((dd0 >> 3) & 3)*16 + (dl & 15);
        bf16x8 ov;
        #pragma unroll
        for (int j = 0; j < 8; ++j) ov[j] = (bf16)acc[j];
        *(bf16x8*)&attF[hbase + f*512 + ln*8] = ov;
    } else if (bid < 160){
        // ---- Wq/oW relayout, 512 threads (FIXED: full 64-row tile load, p<8)
        int lb2 = bid - 32;
        const float* W = (lb2 < 64) ? Wq : oW;
        bf16* Wst = (lb2 < 64) ? wqS : owS;
        int lb = lb2 & 63;
        int k0 = (lb & 7)*64, n0 = (lb >> 3)*64;
        float (*tile)[65] = (float(*)[65])smem;
        int c = t & 63, r8 = t >> 6;           // 0..7
        #pragma unroll
        for (int p = 0; p < 8; ++p){ int r = p*8 + r8; tile[r][c] = W[(size_t)(k0+r)*D + n0 + c]; }
        __syncthreads();
        int sel = t >> 8;                       // 0 or 1 -> half
        int oct = (t >> 6) & 3, col = t & 63;
        {
            int kk = (lb & 7)*2 + sel;
            bf16x8 ov;
            #pragma unroll
            for (int j = 0; j < 8; ++j) ov[j] = (bf16)tile[sel*32 + oct*8 + j][col];
            *(bf16x8*)&Wst[(size_t)kk*SLICE + (n0+col)*32 + oct*8] = ov;
        }
    } else {
        // ---- ss, 512 threads
        float (*semb)[TE] = (float(*)[TE])smem;                 // 32 KB
        float (*red)[64]  = (float(*)[64])(smem + 4*TE*4);      // 8 KB
        int c = bid - 160;
        for (int i = t; i < TE; i += 512)
            #pragma unroll
            for (int b = 0; b < B; ++b){ float e = emb[b*TE + i]; semb[b][i] = e * sigmoidf_(e); }
        __syncthreads();
        int o = t & 15, p = t >> 4;            // p in 0..31
        int j = c*16 + o;
        float acc[B] = {0.f,0.f,0.f,0.f};
        for (int i = 0; i < 64; ++i){
            int e = p*64 + i;
            float wv = emb_W[(size_t)e*1024 + j];
            #pragma unroll
            for (int b = 0; b < B; ++b) acc[b] += semb[b][e] * wv;
        }
        #pragma unroll
        for (int b = 0; b < B; ++b) red[p][b*16 + o] = acc[b];
        __syncthreads();
        if (t < 64){
            int b = t >> 4, o2 = t & 15;
            int j2 = c*16 + o2;
            float s = 0.f;
            #pragma unroll
            for (int pp = 0; pp < 32; ++pp) s += red[pp][b*16 + o2];
            ss[b*1024 + j2] = s + emb_b[j2];
        }
    }
}

// ======== rolled, register-double-buffered GEMM over K=512 (+T5 setprio) — r15 exact ========
__device__ __forceinline__ void gemm_body(const bf16* __restrict__ wfrag,
                                          const bf16* __restrict__ afrag,
                                          f32x4 (&acc)[4][4]){
    bf16x8 b0[4], b1[4];
    #pragma unroll
    for (int nt = 0; nt < 4; ++nt) b0[nt] = *(const bf16x8*)&wfrag[nt*512];
    #pragma unroll
    for (int nt = 0; nt < 4; ++nt) b1[nt] = *(const bf16x8*)&wfrag[SLICE + nt*512];
    const bf16* wp = wfrag + 2*(size_t)SLICE;
    const bf16* ap = afrag;
    __builtin_amdgcn_s_setprio(1);
    for (int kk = 0; kk < 14; kk += 2){
        bf16x8 aa[4];
        #pragma unroll
        for (int mt = 0; mt < 4; ++mt) aa[mt] = *(const bf16x8*)&ap[mt*16*AS];
        #pragma unroll
        for (int nt = 0; nt < 4; ++nt)
            #pragma unroll
            for (int mt = 0; mt < 4; ++mt)
                acc[mt][nt] = __builtin_amdgcn_mfma_f32_16x16x32_bf16(aa[mt], b0[nt], acc[mt][nt], 0, 0, 0);
        #pragma unroll
        for (int nt = 0; nt < 4; ++nt) b0[nt] = *(const bf16x8*)&wp[nt*512];
        #pragma unroll
        for (int mt = 0; mt < 4; ++mt) aa[mt] = *(const bf16x8*)&ap[mt*16*AS + 32];
        #pragma unroll
        for (int nt = 0; nt < 4; ++nt)
            #pragma unroll
            for (int mt = 0; mt < 4; ++mt)
                acc[mt][nt] = __builtin_amdgcn_mfma_f32_16x16x32_bf16(aa[mt], b1[nt], acc[mt][nt], 0, 0, 0);
        #pragma unroll
        for (int nt = 0; nt < 4; ++nt) b1[nt] = *(const bf16x8*)&wp[SLICE + nt*512];
        wp += 2*(size_t)SLICE; ap += 64;
    }
    {
        bf16x8 aa[4];
        #pragma unroll
        for (int mt = 0; mt < 4; ++mt) aa[mt] = *(const bf16x8*)&ap[mt*16*AS];
        #pragma unroll
        for (int nt = 0; nt < 4; ++nt)
            #pragma unroll
            for (int mt = 0; mt < 4; ++mt)
                acc[mt][nt] = __builtin_amdgcn_mfma_f32_16x16x32_bf16(aa[mt], b0[nt], acc[mt][nt], 0, 0, 0);
        #pragma unroll
        for (int mt = 0; mt < 4; ++mt) aa[mt] = *(const bf16x8*)&ap[mt*16*AS + 32];
        #pragma unroll
        for (int nt = 0; nt < 4; ++nt)
            #pragma unroll
            for (int mt = 0; mt < 4; ++mt)
                acc[mt][nt] = __builtin_amdgcn_mfma_f32_16x16x32_bf16(aa[mt], b1[nt], acc[mt][nt], 0, 0, 0);
    }
    __builtin_amdgcn_s_setprio(0);
}

// ======== main fused kernel (r15 exact): 64 rows/block, 8 waves, 2 blocks/CU ========
__global__ __launch_bounds__(512, 4) void k_main(
    const float* __restrict__ x, const bf16* __restrict__ WqS, const float* __restrict__ bq,
    const float* __restrict__ lg, const float* __restrict__ lb,
    const bf16* __restrict__ attF, const float* __restrict__ ssb,
    const float* __restrict__ sg, const float* __restrict__ sb,
    const bf16* __restrict__ oWS, const float* __restrict__ ob,
    float* __restrict__ out){
    __shared__ __align__(16) bf16 Abuf[MR*AS];
    __shared__ float st_s[MR][8];
    __shared__ float st_q[MR][8];
    const int t = threadIdx.x, w = t >> 6, lane = t & 63;
    const int l15 = lane & 15, grp = lane >> 4;
    const long g0 = (long)blockIdx.x * MR;
    const int b = (int)(g0 / T);
    const int wb = w * 64;
    const size_t fragoff = (size_t)w*2048 + (size_t)l15*32 + (size_t)grp*8;

    {
        float4 lg0 = *(const float4*)&lg[lane*8], lg1 = *(const float4*)&lg[lane*8+4];
        float4 lb0 = *(const float4*)&lb[lane*8], lb1 = *(const float4*)&lb[lane*8+4];
        #pragma unroll 2
        for (int rr = 0; rr < 8; ++rr){
            int r = w*8 + rr;
            const float* xp = &x[(size_t)(g0 + r)*D + lane*8];
            float4 v0 = *(const float4*)xp, v1 = *(const float4*)(xp+4);
            float s  = v0.x+v0.y+v0.z+v0.w + v1.x+v1.y+v1.z+v1.w;
            float sq = v0.x*v0.x+v0.y*v0.y+v0.z*v0.z+v0.w*v0.w
                     + v1.x*v1.x+v1.y*v1.y+v1.z*v1.z+v1.w*v1.w;
            #pragma unroll
            for (int o = 32; o; o >>= 1){ s += __shfl_xor(s,o); sq += __shfl_xor(sq,o); }
            float m = s*(1.f/D), var = sq*(1.f/D) - m*m, rstd = rsqrtf(var + 1e-5f);
            bf16x8 ov;
            ov[0] = (bf16)((v0.x-m)*rstd*lg0.x + lb0.x);
            ov[1] = (bf16)((v0.y-m)*rstd*lg0.y + lb0.y);
            ov[2] = (bf16)((v0.z-m)*rstd*lg0.z + lb0.z);
            ov[3] = (bf16)((v0.w-m)*rstd*lg0.w + lb0.w);
            ov[4] = (bf16)((v1.x-m)*rstd*lg1.x + lb1.x);
            ov[5] = (bf16)((v1.y-m)*rstd*lg1.y + lb1.y);
            ov[6] = (bf16)((v1.z-m)*rstd*lg1.z + lb1.z);
            ov[7] = (bf16)((v1.w-m)*rstd*lg1.w + lb1.w);
            *(bf16x8*)&Abuf[r*AS + lane*8] = ov;
        }
    }
    __syncthreads();

    f32x4 acc[4][4];
    #pragma unroll
    for (int mt = 0; mt < 4; ++mt)
        #pragma unroll
        for (int nt = 0; nt < 4; ++nt) acc[mt][nt] = (f32x4){0.f,0.f,0.f,0.f};
    gemm_body(WqS + fragoff, &Abuf[l15*AS + grp*8], acc);

    bf16x8 bfr[2][4];
    {
        const bf16* ab = attF + (((size_t)b*H + w) << 12);
        #pragma unroll
        for (int ks = 0; ks < 2; ++ks)
            #pragma unroll
            for (int n4 = 0; n4 < 4; ++n4)
                bfr[ks][n4] = *(const bf16x8*)&ab[(n4*2 + ks)*512 + lane*8];
    }

    {
        float bqv[4];
        #pragma unroll
        for (int nt = 0; nt < 4; ++nt) bqv[nt] = bq[wb + nt*16 + l15];
        #pragma unroll
        for (int mt = 0; mt < 4; ++mt)
            #pragma unroll
            for (int r = 0; r < 4; ++r){
                float v0 = acc[mt][0][r] + bqv[0];
                float v1 = acc[mt][1][r] + bqv[1];
                float v2 = acc[mt][2][r] + bqv[2];
                float v3 = acc[mt][3][r] + bqv[3];
                float mx = fmaxf(fmaxf(v0,v1), fmaxf(v2,v3));
                #pragma unroll
                for (int o = 1; o < 16; o <<= 1) mx = fmaxf(mx, __shfl_xor(mx, o));
                float e0 = __expf(v0-mx), e1 = __expf(v1-mx), e2 = __expf(v2-mx), e3 = __expf(v3-mx);
                float sden = e0+e1+e2+e3;
                #pragma unroll
                for (int o = 1; o < 16; o <<= 1) sden += __shfl_xor(sden, o);
                float inv = 1.f/sden;
                acc[mt][0][r] = e0*inv; acc[mt][1][r] = e1*inv;
                acc[mt][2][r] = e2*inv; acc[mt][3][r] = e3*inv;
            }
    }
    __syncthreads();

    #pragma unroll
    for (int mt = 0; mt < 4; ++mt)
        #pragma unroll
        for (int nt = 0; nt < 4; ++nt)
            #pragma unroll
            for (int r = 0; r < 4; ++r)
                Abuf[(mt*16 + grp*4 + r)*AS + wb + nt*16 + l15] = (bf16)acc[mt][nt][r];
    asm volatile("s_waitcnt lgkmcnt(0)" ::: "memory");
    __builtin_amdgcn_sched_barrier(0);

    #pragma unroll
    for (int mt = 0; mt < 4; ++mt)
        #pragma unroll
        for (int nt = 0; nt < 4; ++nt) acc[mt][nt] = (f32x4){0.f,0.f,0.f,0.f};
    #pragma unroll
    for (int ks = 0; ks < 2; ++ks){
        bf16x8 qa[4];
        #pragma unroll
        for (int mt = 0; mt < 4; ++mt)
            qa[mt] = *(const bf16x8*)&Abuf[(mt*16 + l15)*AS + wb + ks*32 + grp*8];
        #pragma unroll
        for (int n4 = 0; n4 < 4; ++n4)
            #pragma unroll
            for (int mt = 0; mt < 4; ++mt)
                acc[mt][n4] = __builtin_amdgcn_mfma_f32_16x16x32_bf16(qa[mt], bfr[ks][n4], acc[mt][n4], 0, 0, 0);
    }

    #pragma unroll
    for (int mt = 0; mt < 4; ++mt)
        #pragma unroll
        for (int r = 0; r < 4; ++r){
            float s = 0.f, q2 = 0.f;
            #pragma unroll
            for (int nt = 0; nt < 4; ++nt){ float v = acc[mt][nt][r]; s += v; q2 += v*v; }
            #pragma unroll
            for (int o = 1; o < 16; o <<= 1){ s += __shfl_xor(s, o); q2 += __shfl_xor(q2, o); }
            if (l15 == 0){ st_s[mt*16 + grp*4 + r][w] = s; st_q[mt*16 + grp*4 + r][w] = q2; }
        }
    __syncthreads();

    {
        float sgv[4], sbv[4], sscv[4], sshv[4];
        #pragma unroll
        for (int nt = 0; nt < 4; ++nt){
            int col = wb + nt*16 + l15;
            sgv[nt] = sg[col]; sbv[nt] = sb[col];
            sscv[nt] = ssb[b*1024 + col]; sshv[nt] = ssb[b*1024 + 512 + col];
        }
        #pragma unroll
        for (int mt = 0; mt < 4; ++mt)
            #pragma unroll
            for (int r = 0; r < 4; ++r){
                int row = mt*16 + grp*4 + r;
                float4 s0 = *(const float4*)&st_s[row][0];
                float4 s1 = *(const float4*)&st_s[row][4];
                float4 q0 = *(const float4*)&st_q[row][0];
                float4 q1 = *(const float4*)&st_q[row][4];
                float m = (s0.x+s0.y+s0.z+s0.w + s1.x+s1.y+s1.z+s1.w)*(1.f/D);
                float var = (q0.x+q0.y+q0.z+q0.w + q1.x+q1.y+q1.z+q1.w)*(1.f/D) - m*m;
                float rstd = rsqrtf(var + 1e-5f);
                #pragma unroll
                for (int nt = 0; nt < 4; ++nt){
                    float yn = (acc[mt][nt][r] - m)*rstd*sgv[nt] + sbv[nt];
                    float h2 = yn*(1.f + sscv[nt]) + sshv[nt];
                    Abuf[row*AS + wb + nt*16 + l15] = (bf16)(h2 * sigmoidf_(h2));
                }
            }
    }
    __syncthreads();

    #pragma unroll
    for (int mt = 0; mt < 4; ++mt)
        #pragma unroll
        for (int nt = 0; nt < 4; ++nt) acc[mt][nt] = (f32x4){0.f,0.f,0.f,0.f};
    gemm_body(oWS + fragoff, &Abuf[l15*AS + grp*8], acc);

    float* scr = (float*)Abuf;
    #pragma unroll
    for (int half = 0; half < 2; ++half){
        __syncthreads();
        #pragma unroll
        for (int mt2 = 0; mt2 < 2; ++mt2){
            int mt = half*2 + mt2;
            #pragma unroll
            for (int nt = 0; nt < 4; ++nt)
                #pragma unroll
                for (int r = 0; r < 4; ++r)
                    scr[(mt2*16 + grp*4 + r)*516 + wb + nt*16 + l15] = acc[mt][nt][r];
        }
        __syncthreads();
        #pragma unroll 2
        for (int i = 0; i < 8; ++i){
            int c = i*512 + t;
            int row = c >> 7, col4 = (c & 127) << 2;
            float4 v  = *(const float4*)&scr[row*516 + col4];
            size_t gi = (size_t)(g0 + half*32 + row)*D + col4;
            float4 xb = *(const float4*)&x[gi];
            float4 o4 = *(const float4*)&ob[col4];
            float4 r4 = {v.x+o4.x+xb.x, v.y+o4.y+xb.y, v.z+o4.z+xb.z, v.w+o4.w+xb.w};
            *(float4*)&out[gi] = r4;
        }
    }
}

extern "C" void kernel_launch(void* const* d_in, const int* in_sizes, int n_in,
                              void* d_out, int out_size, void* d_ws, size_t ws_size,
                              hipStream_t stream){
    const float* x     = (const float*)d_in[0];
    const float* xf    = (const float*)d_in[1];
    const float* emb   = (const float*)d_in[2];
    const float* Wq    = (const float*)d_in[3];
    const float* bq    = (const float*)d_in[4];
    const float* Wk    = (const float*)d_in[5];
    const float* bk    = (const float*)d_in[6];
    const float* Wv    = (const float*)d_in[7];
    const float* bv    = (const float*)d_in[8];
    const float* ln_g  = (const float*)d_in[9];
    const float* ln_b  = (const float*)d_in[10];
    const float* tln_g = (const float*)d_in[11];
    const float* tln_b = (const float*)d_in[12];
    const float* emb_W = (const float*)d_in[13];
    const float* emb_b = (const float*)d_in[14];
    const float* sn_g  = (const float*)d_in[15];
    const float* sn_b  = (const float*)d_in[16];
    const float* out_W = (const float*)d_in[17];
    const float* out_b = (const float*)d_in[18];
    float* out = (float*)d_out;

    // workspace carve
    float* ssb  = (float*)d_ws;                          // B*1024 f32
    bf16*  kbuf = (bf16*)(ssb + B*1024);                 // B*NN*D bf16
    bf16*  vbuf = kbuf + (size_t)B*NN*D;                 // B*NN*D bf16
    bf16*  attF = vbuf + (size_t)B*NN*D;                 // B*H*DH*DH bf16
    bf16*  wqS  = attF + (size_t)B*H*DH*DH;              // D*D bf16 (staged)
    bf16*  owS  = wqS  + (size_t)D*D;                    // D*D bf16 (staged)
    bf16*  wkS  = owS  + (size_t)D*D;                    // L*D bf16 (staged)
    bf16*  wvS  = wkS  + (size_t)L*D;                    // L*D bf16 (staged)

    k_prepKV<<<dim3(192),     dim3(256), 0, stream>>>(Wk, Wv, wkS, wvS);
    k_kv    <<<dim3(B*NN/16), dim3(512), 0, stream>>>(xf, wkS, wvS, bk, bv,
                                                      tln_g, tln_b, kbuf, vbuf);
    k_rest  <<<dim3(224),     dim3(512), 0, stream>>>(kbuf, vbuf, attF, Wq, out_W, wqS, owS,
                                                      emb, emb_W, emb_b, ssb);
    k_main  <<<dim3(B*T/MR),  dim3(512), 0, stream>>>(x, wqS, bq, ln_g, ln_b, attF, ssb,
                                                      sn_g, sn_b, owS, out_b, out);
}

// Round 20
// 130.313 us; speedup vs baseline: 1.2526x; 1.0194x over previous
//
#include <hip/hip_runtime.h>
#include <math.h>
#include <stdint.h>

#define B 4
#define T 8192
#define D 512
#define NN 256
#define L 768
#define TE 2048
#define H 8
#define DH 64
#define MR 64
#define AS 520          // Abuf row stride (bf16 elems)
#define SLICE 16384     // elems per 32-K staged slice (512 cols * 32 k)
#define XST 776         // k_kv LDS row stride (bf16), 16B-aligned

typedef __bf16 bf16;
typedef bf16  bf16x4 __attribute__((ext_vector_type(4)));
typedef bf16  bf16x8 __attribute__((ext_vector_type(8)));
typedef float f32x4  __attribute__((ext_vector_type(4)));

__device__ __forceinline__ float sigmoidf_(float x){ return 1.0f/(1.0f+__expf(-x)); }

// ======== k_prepKV: Wk/Wv relayout ONLY (critical path for k_kv) ========
__global__ __launch_bounds__(256) void k_prepKV(
    const float* __restrict__ Wk, const float* __restrict__ Wv,
    bf16* __restrict__ wkS, bf16* __restrict__ wvS){
    __shared__ __align__(16) float tile[64][65];
    const int bid = blockIdx.x, t = threadIdx.x;
    const float* W = (bid < 96) ? Wk : Wv;
    bf16* Wst = (bid < 96) ? wkS : wvS;
    int lb = (bid < 96) ? bid : bid - 96;
    int k0 = (lb % 12)*64, n0 = (lb / 12)*64;
    int kkbase = (lb % 12)*2;
    int c = t & 63, r4 = t >> 6;
    #pragma unroll
    for (int p = 0; p < 16; ++p){ int r = p*4 + r4; tile[r][c] = W[(size_t)(k0+r)*D + n0 + c]; }
    __syncthreads();
    int oct = t >> 6, col = t & 63;
    #pragma unroll
    for (int half = 0; half < 2; ++half){
        int kk = kkbase + half;
        bf16x8 ov;
        #pragma unroll
        for (int j = 0; j < 8; ++j) ov[j] = (bf16)tile[half*32 + oct*8 + j][col];
        *(bf16x8*)&Wst[(size_t)kk*SLICE + (n0+col)*32 + oct*8] = ov;
    }
}

// ======== k_kv: LN(xf) + MFMA k/v projection (r17 exact) ========
__global__ __launch_bounds__(512) void k_kv(
    const float* __restrict__ xf, const bf16* __restrict__ wkS, const bf16* __restrict__ wvS,
    const float* __restrict__ bk, const float* __restrict__ bv,
    const float* __restrict__ tg, const float* __restrict__ tb,
    bf16* __restrict__ kbuf, bf16* __restrict__ vbuf){
    __shared__ __align__(16) bf16 xfn[16*XST];
    const int t = threadIdx.x, w = t >> 6, lane = t & 63;
    const int l15 = lane & 15, grp = lane >> 4;
    const int g0 = blockIdx.x * 16;
    const int wb = w * 64;
    #pragma unroll
    for (int rr = 0; rr < 2; ++rr){
        int r = w*2 + rr, g = g0 + r;
        float vals[12];
        float s = 0.f, sq = 0.f;
        #pragma unroll
        for (int i = 0; i < 12; ++i){ float v = xf[(size_t)g*L + lane*12 + i]; vals[i] = v; s += v; sq += v*v; }
        #pragma unroll
        for (int o = 32; o; o >>= 1){ s += __shfl_xor(s, o); sq += __shfl_xor(sq, o); }
        float m = s / L; float var = sq / L - m*m;
        float rstd = rsqrtf(var + 1e-5f);
        #pragma unroll
        for (int i = 0; i < 12; ++i){
            int l = lane*12 + i;
            xfn[r*XST + l] = (bf16)((vals[i]-m)*rstd*tg[l] + tb[l]);
        }
    }
    __syncthreads();
    f32x4 ak[4], av[4];
    #pragma unroll
    for (int nt = 0; nt < 4; ++nt){ ak[nt] = (f32x4){0.f,0.f,0.f,0.f}; av[nt] = (f32x4){0.f,0.f,0.f,0.f}; }
    const bf16* wkf = wkS + (size_t)wb*32 + (size_t)l15*32 + (size_t)grp*8;
    const bf16* wvf = wvS + (size_t)wb*32 + (size_t)l15*32 + (size_t)grp*8;
    for (int kk = 0; kk < 24; ++kk){
        bf16x8 aa = *(const bf16x8*)&xfn[l15*XST + kk*32 + grp*8];
        #pragma unroll
        for (int nt = 0; nt < 4; ++nt){
            bf16x8 bb = *(const bf16x8*)&wkf[(size_t)kk*SLICE + nt*512];
            ak[nt] = __builtin_amdgcn_mfma_f32_16x16x32_bf16(aa, bb, ak[nt], 0, 0, 0);
        }
        #pragma unroll
        for (int nt = 0; nt < 4; ++nt){
            bf16x8 bb = *(const bf16x8*)&wvf[(size_t)kk*SLICE + nt*512];
            av[nt] = __builtin_amdgcn_mfma_f32_16x16x32_bf16(aa, bb, av[nt], 0, 0, 0);
        }
    }
    #pragma unroll
    for (int nt = 0; nt < 4; ++nt){
        int col = wb + nt*16 + l15;
        float bkc = bk[col], bvc = bv[col];
        #pragma unroll
        for (int r = 0; r < 4; ++r){
            size_t gi = (size_t)(g0 + grp*4 + r)*D + col;
            kbuf[gi] = (bf16)(ak[nt][r] + bkc);
            vbuf[gi] = (bf16)(av[nt][r] + bvc);
        }
    }
}

// ======== k_rest: [0,32) attn state | [32,160) Wq/oW relayout | [160,224) ss ========
__global__ __launch_bounds__(512) void k_rest(
    const bf16* __restrict__ kbuf, const bf16* __restrict__ vbuf, bf16* __restrict__ attF,
    const float* __restrict__ Wq, const float* __restrict__ oW,
    bf16* __restrict__ wqS, bf16* __restrict__ owS,
    const float* __restrict__ emb, const float* __restrict__ emb_W,
    const float* __restrict__ emb_b, float* __restrict__ ss){
    __shared__ __align__(16) char smem[135168];
    const int bid = blockIdx.x, t = threadIdx.x;
    if (bid < 32){
        float* kh = (float*)smem;
        float* vh = kh + NN*DH;
        float (*pm)[DH] = (float(*)[DH])(vh + NN*DH);
        float (*ps)[DH] = pm + 8;
        int h = bid & 7, b = bid >> 3;
        for (int k = 0; k < NN*DH/512; ++k){
            int m = k*512 + t;
            int n = m >> 6, dl = m & 63;
            size_t src = (size_t)(b*NN + n)*D + h*DH + dl;
            kh[m] = (float)kbuf[src]; vh[m] = (float)vbuf[src];
        }
        __syncthreads();
        int d = t & 63, c = t >> 6;
        float mx = -1e30f;
        for (int n = c*32; n < c*32+32; ++n) mx = fmaxf(mx, kh[n*DH + d]);
        pm[c][d] = mx;
        __syncthreads();
        mx = pm[0][d];
        #pragma unroll
        for (int cc = 1; cc < 8; ++cc) mx = fmaxf(mx, pm[cc][d]);
        float s = 0.f;
        for (int n = c*32; n < c*32+32; ++n){ float e = __expf(kh[n*DH + d] - mx); kh[n*DH + d] = e; s += e; }
        ps[c][d] = s;
        __syncthreads();
        float sden = ps[0][d];
        #pragma unroll
        for (int cc = 1; cc < 8; ++cc) sden += ps[cc][d];
        float inv = 1.f/sden;
        for (int n = c*32; n < c*32+32; ++n) kh[n*DH + d] *= inv;
        __syncthreads();
        int dl = t >> 3, dd0 = (t & 7)*8;
        float acc[8];
        #pragma unroll
        for (int i = 0; i < 8; ++i) acc[i] = 0.f;
        for (int n = 0; n < NN; ++n){
            float vv = vh[n*DH + dl];
            #pragma unroll
            for (int i = 0; i < 8; ++i) acc[i] += kh[n*DH + dd0 + i] * vv;
        }
        size_t hbase = ((size_t)(b*H + h)) << 12;
        int f  = (dl >> 4)*2 + (dd0 >> 5);
        int ln = ((dd0 >> 3) & 3)*16 + (dl & 15);
        bf16x8 ov;
        #pragma unroll
        for (int j = 0; j < 8; ++j) ov[j] = (bf16)acc[j];
        *(bf16x8*)&attF[hbase + f*512 + ln*8] = ov;
    } else if (bid < 160){
        int lb2 = bid - 32;
        const float* W = (lb2 < 64) ? Wq : oW;
        bf16* Wst = (lb2 < 64) ? wqS : owS;
        int lb = lb2 & 63;
        int k0 = (lb & 7)*64, n0 = (lb >> 3)*64;
        float (*tile)[65] = (float(*)[65])smem;
        int c = t & 63, r8 = t >> 6;
        #pragma unroll
        for (int p = 0; p < 8; ++p){ int r = p*8 + r8; tile[r][c] = W[(size_t)(k0+r)*D + n0 + c]; }
        __syncthreads();
        int sel = t >> 8;
        int oct = (t >> 6) & 3, col = t & 63;
        {
            int kk = (lb & 7)*2 + sel;
            bf16x8 ov;
            #pragma unroll
            for (int j = 0; j < 8; ++j) ov[j] = (bf16)tile[sel*32 + oct*8 + j][col];
            *(bf16x8*)&Wst[(size_t)kk*SLICE + (n0+col)*32 + oct*8] = ov;
        }
    } else {
        float (*semb)[TE] = (float(*)[TE])smem;
        float (*red)[64]  = (float(*)[64])(smem + 4*TE*4);
        int c = bid - 160;
        for (int i = t; i < TE; i += 512)
            #pragma unroll
            for (int b = 0; b < B; ++b){ float e = emb[b*TE + i]; semb[b][i] = e * sigmoidf_(e); }
        __syncthreads();
        int o = t & 15, p = t >> 4;
        int j = c*16 + o;
        float acc[B] = {0.f,0.f,0.f,0.f};
        for (int i = 0; i < 64; ++i){
            int e = p*64 + i;
            float wv = emb_W[(size_t)e*1024 + j];
            #pragma unroll
            for (int b = 0; b < B; ++b) acc[b] += semb[b][e] * wv;
        }
        #pragma unroll
        for (int b = 0; b < B; ++b) red[p][b*16 + o] = acc[b];
        __syncthreads();
        if (t < 64){
            int b = t >> 4, o2 = t & 15;
            int j2 = c*16 + o2;
            float s = 0.f;
            #pragma unroll
            for (int pp = 0; pp < 32; ++pp) s += red[pp][b*16 + o2];
            ss[b*1024 + j2] = s + emb_b[j2];
        }
    }
}

// ======== rolled GEMM (r15 exact): acc[mt][nt], D = Abuf-A x W-B ========
__device__ __forceinline__ void gemm_body(const bf16* __restrict__ wfrag,
                                          const bf16* __restrict__ afrag,
                                          f32x4 (&acc)[4][4]){
    bf16x8 b0[4], b1[4];
    #pragma unroll
    for (int nt = 0; nt < 4; ++nt) b0[nt] = *(const bf16x8*)&wfrag[nt*512];
    #pragma unroll
    for (int nt = 0; nt < 4; ++nt) b1[nt] = *(const bf16x8*)&wfrag[SLICE + nt*512];
    const bf16* wp = wfrag + 2*(size_t)SLICE;
    const bf16* ap = afrag;
    __builtin_amdgcn_s_setprio(1);
    for (int kk = 0; kk < 14; kk += 2){
        bf16x8 aa[4];
        #pragma unroll
        for (int mt = 0; mt < 4; ++mt) aa[mt] = *(const bf16x8*)&ap[mt*16*AS];
        #pragma unroll
        for (int nt = 0; nt < 4; ++nt)
            #pragma unroll
            for (int mt = 0; mt < 4; ++mt)
                acc[mt][nt] = __builtin_amdgcn_mfma_f32_16x16x32_bf16(aa[mt], b0[nt], acc[mt][nt], 0, 0, 0);
        #pragma unroll
        for (int nt = 0; nt < 4; ++nt) b0[nt] = *(const bf16x8*)&wp[nt*512];
        #pragma unroll
        for (int mt = 0; mt < 4; ++mt) aa[mt] = *(const bf16x8*)&ap[mt*16*AS + 32];
        #pragma unroll
        for (int nt = 0; nt < 4; ++nt)
            #pragma unroll
            for (int mt = 0; mt < 4; ++mt)
                acc[mt][nt] = __builtin_amdgcn_mfma_f32_16x16x32_bf16(aa[mt], b1[nt], acc[mt][nt], 0, 0, 0);
        #pragma unroll
        for (int nt = 0; nt < 4; ++nt) b1[nt] = *(const bf16x8*)&wp[SLICE + nt*512];
        wp += 2*(size_t)SLICE; ap += 64;
    }
    {
        bf16x8 aa[4];
        #pragma unroll
        for (int mt = 0; mt < 4; ++mt) aa[mt] = *(const bf16x8*)&ap[mt*16*AS];
        #pragma unroll
        for (int nt = 0; nt < 4; ++nt)
            #pragma unroll
            for (int mt = 0; mt < 4; ++mt)
                acc[mt][nt] = __builtin_amdgcn_mfma_f32_16x16x32_bf16(aa[mt], b0[nt], acc[mt][nt], 0, 0, 0);
        #pragma unroll
        for (int mt = 0; mt < 4; ++mt) aa[mt] = *(const bf16x8*)&ap[mt*16*AS + 32];
        #pragma unroll
        for (int nt = 0; nt < 4; ++nt)
            #pragma unroll
            for (int mt = 0; mt < 4; ++mt)
                acc[mt][nt] = __builtin_amdgcn_mfma_f32_16x16x32_bf16(aa[mt], b1[nt], acc[mt][nt], 0, 0, 0);
    }
    __builtin_amdgcn_s_setprio(0);
}

// ======== transposed GEMM: same loads, mfma operands swapped -> acc[mtO][ntT] = q^T ========
// D[i][j] = sum_k Wq[k][outcol i] * LN(x)[token j][k]; C layout: outcol=grp*4+r(+16*mtO), token=l15(+16*ntT)
__device__ __forceinline__ void gemm_bodyT(const bf16* __restrict__ wfrag,
                                           const bf16* __restrict__ afrag,
                                           f32x4 (&acc)[4][4]){
    bf16x8 b0[4], b1[4];
    #pragma unroll
    for (int nt = 0; nt < 4; ++nt) b0[nt] = *(const bf16x8*)&wfrag[nt*512];
    #pragma unroll
    for (int nt = 0; nt < 4; ++nt) b1[nt] = *(const bf16x8*)&wfrag[SLICE + nt*512];
    const bf16* wp = wfrag + 2*(size_t)SLICE;
    const bf16* ap = afrag;
    __builtin_amdgcn_s_setprio(1);
    for (int kk = 0; kk < 14; kk += 2){
        bf16x8 aa[4];
        #pragma unroll
        for (int mt = 0; mt < 4; ++mt) aa[mt] = *(const bf16x8*)&ap[mt*16*AS];
        #pragma unroll
        for (int nt = 0; nt < 4; ++nt)
            #pragma unroll
            for (int mt = 0; mt < 4; ++mt)
                acc[nt][mt] = __builtin_amdgcn_mfma_f32_16x16x32_bf16(b0[nt], aa[mt], acc[nt][mt], 0, 0, 0);
        #pragma unroll
        for (int nt = 0; nt < 4; ++nt) b0[nt] = *(const bf16x8*)&wp[nt*512];
        #pragma unroll
        for (int mt = 0; mt < 4; ++mt) aa[mt] = *(const bf16x8*)&ap[mt*16*AS + 32];
        #pragma unroll
        for (int nt = 0; nt < 4; ++nt)
            #pragma unroll
            for (int mt = 0; mt < 4; ++mt)
                acc[nt][mt] = __builtin_amdgcn_mfma_f32_16x16x32_bf16(b1[nt], aa[mt], acc[nt][mt], 0, 0, 0);
        #pragma unroll
        for (int nt = 0; nt < 4; ++nt) b1[nt] = *(const bf16x8*)&wp[SLICE + nt*512];
        wp += 2*(size_t)SLICE; ap += 64;
    }
    {
        bf16x8 aa[4];
        #pragma unroll
        for (int mt = 0; mt < 4; ++mt) aa[mt] = *(const bf16x8*)&ap[mt*16*AS];
        #pragma unroll
        for (int nt = 0; nt < 4; ++nt)
            #pragma unroll
            for (int mt = 0; mt < 4; ++mt)
                acc[nt][mt] = __builtin_amdgcn_mfma_f32_16x16x32_bf16(b0[nt], aa[mt], acc[nt][mt], 0, 0, 0);
        #pragma unroll
        for (int mt = 0; mt < 4; ++mt) aa[mt] = *(const bf16x8*)&ap[mt*16*AS + 32];
        #pragma unroll
        for (int nt = 0; nt < 4; ++nt)
            #pragma unroll
            for (int mt = 0; mt < 4; ++mt)
                acc[nt][mt] = __builtin_amdgcn_mfma_f32_16x16x32_bf16(b1[nt], aa[mt], acc[nt][mt], 0, 0, 0);
    }
    __builtin_amdgcn_s_setprio(0);
}

// ======== main fused kernel: q^T GEMM1 + cheap softmax; rest r15-exact ========
__global__ __launch_bounds__(512, 4) void k_main(
    const float* __restrict__ x, const bf16* __restrict__ WqS, const float* __restrict__ bq,
    const float* __restrict__ lg, const float* __restrict__ lb,
    const bf16* __restrict__ attF, const float* __restrict__ ssb,
    const float* __restrict__ sg, const float* __restrict__ sb,
    const bf16* __restrict__ oWS, const float* __restrict__ ob,
    float* __restrict__ out){
    __shared__ __align__(16) bf16 Abuf[MR*AS];
    __shared__ float st_s[MR][8];
    __shared__ float st_q[MR][8];
    const int t = threadIdx.x, w = t >> 6, lane = t & 63;
    const int l15 = lane & 15, grp = lane >> 4;
    const long g0 = (long)blockIdx.x * MR;
    const int b = (int)(g0 / T);
    const int wb = w * 64;
    const size_t fragoff = (size_t)w*2048 + (size_t)l15*32 + (size_t)grp*8;

    // ---- phase A: LN(x) -> Abuf bf16 (unroll 4: more loads in flight)
    {
        float4 lg0 = *(const float4*)&lg[lane*8], lg1 = *(const float4*)&lg[lane*8+4];
        float4 lb0 = *(const float4*)&lb[lane*8], lb1 = *(const float4*)&lb[lane*8+4];
        #pragma unroll 4
        for (int rr = 0; rr < 8; ++rr){
            int r = w*8 + rr;
            const float* xp = &x[(size_t)(g0 + r)*D + lane*8];
            float4 v0 = *(const float4*)xp, v1 = *(const float4*)(xp+4);
            float s  = v0.x+v0.y+v0.z+v0.w + v1.x+v1.y+v1.z+v1.w;
            float sq = v0.x*v0.x+v0.y*v0.y+v0.z*v0.z+v0.w*v0.w
                     + v1.x*v1.x+v1.y*v1.y+v1.z*v1.z+v1.w*v1.w;
            #pragma unroll
            for (int o = 32; o; o >>= 1){ s += __shfl_xor(s,o); sq += __shfl_xor(sq,o); }
            float m = s*(1.f/D), var = sq*(1.f/D) - m*m, rstd = rsqrtf(var + 1e-5f);
            bf16x8 ov;
            ov[0] = (bf16)((v0.x-m)*rstd*lg0.x + lb0.x);
            ov[1] = (bf16)((v0.y-m)*rstd*lg0.y + lb0.y);
            ov[2] = (bf16)((v0.z-m)*rstd*lg0.z + lb0.z);
            ov[3] = (bf16)((v0.w-m)*rstd*lg0.w + lb0.w);
            ov[4] = (bf16)((v1.x-m)*rstd*lg1.x + lb1.x);
            ov[5] = (bf16)((v1.y-m)*rstd*lg1.y + lb1.y);
            ov[6] = (bf16)((v1.z-m)*rstd*lg1.z + lb1.z);
            ov[7] = (bf16)((v1.w-m)*rstd*lg1.w + lb1.w);
            *(bf16x8*)&Abuf[r*AS + lane*8] = ov;
        }
    }
    __syncthreads();

    // ---- GEMM1 (transposed): acc[mtO][ntT] = q^T
    f32x4 acc[4][4];
    #pragma unroll
    for (int mt = 0; mt < 4; ++mt)
        #pragma unroll
        for (int nt = 0; nt < 4; ++nt) acc[mt][nt] = (f32x4){0.f,0.f,0.f,0.f};
    gemm_bodyT(WqS + fragoff, &Abuf[l15*AS + grp*8], acc);

    // ---- attF prefetch (L2) — consumed in phase D
    bf16x8 bfr[2][4];
    {
        const bf16* ab = attF + (((size_t)b*H + w) << 12);
        #pragma unroll
        for (int ks = 0; ks < 2; ++ks)
            #pragma unroll
            for (int n4 = 0; n4 < 4; ++n4)
                bfr[ks][n4] = *(const bf16x8*)&ab[(n4*2 + ks)*512 + lane*8];
    }

    // ---- softmax on q^T: bias (r-contiguous float4) + per-token reduce (2 shuffles)
    {
        #pragma unroll
        for (int mtO = 0; mtO < 4; ++mtO){
            float4 b4 = *(const float4*)&bq[wb + mtO*16 + grp*4];
            #pragma unroll
            for (int ntT = 0; ntT < 4; ++ntT){
                acc[mtO][ntT][0] += b4.x; acc[mtO][ntT][1] += b4.y;
                acc[mtO][ntT][2] += b4.z; acc[mtO][ntT][3] += b4.w;
            }
        }
        #pragma unroll
        for (int ntT = 0; ntT < 4; ++ntT){
            float mx = -1e30f;
            #pragma unroll
            for (int mtO = 0; mtO < 4; ++mtO)
                #pragma unroll
                for (int r = 0; r < 4; ++r) mx = fmaxf(mx, acc[mtO][ntT][r]);
            mx = fmaxf(mx, __shfl_xor(mx, 16));
            mx = fmaxf(mx, __shfl_xor(mx, 32));
            float sden = 0.f;
            #pragma unroll
            for (int mtO = 0; mtO < 4; ++mtO)
                #pragma unroll
                for (int r = 0; r < 4; ++r){
                    float e = __expf(acc[mtO][ntT][r] - mx);
                    acc[mtO][ntT][r] = e; sden += e;
                }
            sden += __shfl_xor(sden, 16);
            sden += __shfl_xor(sden, 32);
            float inv = 1.f/sden;
            #pragma unroll
            for (int mtO = 0; mtO < 4; ++mtO)
                #pragma unroll
                for (int r = 0; r < 4; ++r) acc[mtO][ntT][r] *= inv;
        }
    }
    __syncthreads();   // all waves done reading Abuf (GEMM1) before overwrite

    // q -> Abuf [token row][own cols], r-contiguous 8B vector writes (wave-local region)
    #pragma unroll
    for (int mtO = 0; mtO < 4; ++mtO)
        #pragma unroll
        for (int ntT = 0; ntT < 4; ++ntT){
            bf16x4 qv;
            #pragma unroll
            for (int r = 0; r < 4; ++r) qv[r] = (bf16)acc[mtO][ntT][r];
            *(bf16x4*)&Abuf[(ntT*16 + l15)*AS + wb + mtO*16 + grp*4] = qv;
        }
    asm volatile("s_waitcnt lgkmcnt(0)" ::: "memory");
    __builtin_amdgcn_sched_barrier(0);

    // ---- phase D: y = q @ att[head w]  (unchanged; Abuf holds q[token][col])
    #pragma unroll
    for (int mt = 0; mt < 4; ++mt)
        #pragma unroll
        for (int nt = 0; nt < 4; ++nt) acc[mt][nt] = (f32x4){0.f,0.f,0.f,0.f};
    #pragma unroll
    for (int ks = 0; ks < 2; ++ks){
        bf16x8 qa[4];
        #pragma unroll
        for (int mt = 0; mt < 4; ++mt)
            qa[mt] = *(const bf16x8*)&Abuf[(mt*16 + l15)*AS + wb + ks*32 + grp*8];
        #pragma unroll
        for (int n4 = 0; n4 < 4; ++n4)
            #pragma unroll
            for (int mt = 0; mt < 4; ++mt)
                acc[mt][n4] = __builtin_amdgcn_mfma_f32_16x16x32_bf16(qa[mt], bfr[ks][n4], acc[mt][n4], 0, 0, 0);
    }

    // ---- LN(y) stats
    #pragma unroll
    for (int mt = 0; mt < 4; ++mt)
        #pragma unroll
        for (int r = 0; r < 4; ++r){
            float s = 0.f, q2 = 0.f;
            #pragma unroll
            for (int nt = 0; nt < 4; ++nt){ float v = acc[mt][nt][r]; s += v; q2 += v*v; }
            #pragma unroll
            for (int o = 1; o < 16; o <<= 1){ s += __shfl_xor(s, o); q2 += __shfl_xor(q2, o); }
            if (l15 == 0){ st_s[mt*16 + grp*4 + r][w] = s; st_q[mt*16 + grp*4 + r][w] = q2; }
        }
    __syncthreads();

    // ---- stylize + silu -> Abuf bf16
    {
        float sgv[4], sbv[4], sscv[4], sshv[4];
        #pragma unroll
        for (int nt = 0; nt < 4; ++nt){
            int col = wb + nt*16 + l15;
            sgv[nt] = sg[col]; sbv[nt] = sb[col];
            sscv[nt] = ssb[b*1024 + col]; sshv[nt] = ssb[b*1024 + 512 + col];
        }
        #pragma unroll
        for (int mt = 0; mt < 4; ++mt)
            #pragma unroll
            for (int r = 0; r < 4; ++r){
                int row = mt*16 + grp*4 + r;
                float4 s0 = *(const float4*)&st_s[row][0];
                float4 s1 = *(const float4*)&st_s[row][4];
                float4 q0 = *(const float4*)&st_q[row][0];
                float4 q1 = *(const float4*)&st_q[row][4];
                float m = (s0.x+s0.y+s0.z+s0.w + s1.x+s1.y+s1.z+s1.w)*(1.f/D);
                float var = (q0.x+q0.y+q0.z+q0.w + q1.x+q1.y+q1.z+q1.w)*(1.f/D) - m*m;
                float rstd = rsqrtf(var + 1e-5f);
                #pragma unroll
                for (int nt = 0; nt < 4; ++nt){
                    float yn = (acc[mt][nt][r] - m)*rstd*sgv[nt] + sbv[nt];
                    float h2 = yn*(1.f + sscv[nt]) + sshv[nt];
                    Abuf[row*AS + wb + nt*16 + l15] = (bf16)(h2 * sigmoidf_(h2));
                }
            }
    }
    __syncthreads();

    // ---- GEMM2
    #pragma unroll
    for (int mt = 0; mt < 4; ++mt)
        #pragma unroll
        for (int nt = 0; nt < 4; ++nt) acc[mt][nt] = (f32x4){0.f,0.f,0.f,0.f};
    gemm_body(oWS + fragoff, &Abuf[l15*AS + grp*8], acc);

    // ---- epilogue
    float* scr = (float*)Abuf;
    #pragma unroll
    for (int half = 0; half < 2; ++half){
        __syncthreads();
        #pragma unroll
        for (int mt2 = 0; mt2 < 2; ++mt2){
            int mt = half*2 + mt2;
            #pragma unroll
            for (int nt = 0; nt < 4; ++nt)
                #pragma unroll
                for (int r = 0; r < 4; ++r)
                    scr[(mt2*16 + grp*4 + r)*516 + wb + nt*16 + l15] = acc[mt][nt][r];
        }
        __syncthreads();
        #pragma unroll 2
        for (int i = 0; i < 8; ++i){
            int c = i*512 + t;
            int row = c >> 7, col4 = (c & 127) << 2;
            float4 v  = *(const float4*)&scr[row*516 + col4];
            size_t gi = (size_t)(g0 + half*32 + row)*D + col4;
            float4 xb = *(const float4*)&x[gi];
            float4 o4 = *(const float4*)&ob[col4];
            float4 r4 = {v.x+o4.x+xb.x, v.y+o4.y+xb.y, v.z+o4.z+xb.z, v.w+o4.w+xb.w};
            *(float4*)&out[gi] = r4;
        }
    }
}

extern "C" void kernel_launch(void* const* d_in, const int* in_sizes, int n_in,
                              void* d_out, int out_size, void* d_ws, size_t ws_size,
                              hipStream_t stream){
    const float* x     = (const float*)d_in[0];
    const float* xf    = (const float*)d_in[1];
    const float* emb   = (const float*)d_in[2];
    const float* Wq    = (const float*)d_in[3];
    const float* bq    = (const float*)d_in[4];
    const float* Wk    = (const float*)d_in[5];
    const float* bk    = (const float*)d_in[6];
    const float* Wv    = (const float*)d_in[7];
    const float* bv    = (const float*)d_in[8];
    const float* ln_g  = (const float*)d_in[9];
    const float* ln_b  = (const float*)d_in[10];
    const float* tln_g = (const float*)d_in[11];
    const float* tln_b = (const float*)d_in[12];
    const float* emb_W = (const float*)d_in[13];
    const float* emb_b = (const float*)d_in[14];
    const float* sn_g  = (const float*)d_in[15];
    const float* sn_b  = (const float*)d_in[16];
    const float* out_W = (const float*)d_in[17];
    const float* out_b = (const float*)d_in[18];
    float* out = (float*)d_out;

    // workspace carve
    float* ssb  = (float*)d_ws;                          // B*1024 f32
    bf16*  kbuf = (bf16*)(ssb + B*1024);                 // B*NN*D bf16
    bf16*  vbuf = kbuf + (size_t)B*NN*D;                 // B*NN*D bf16
    bf16*  attF = vbuf + (size_t)B*NN*D;                 // B*H*DH*DH bf16
    bf16*  wqS  = attF + (size_t)B*H*DH*DH;              // D*D bf16 (staged)
    bf16*  owS  = wqS  + (size_t)D*D;                    // D*D bf16 (staged)
    bf16*  wkS  = owS  + (size_t)D*D;                    // L*D bf16 (staged)
    bf16*  wvS  = wkS  + (size_t)L*D;                    // L*D bf16 (staged)

    k_prepKV<<<dim3(192),     dim3(256), 0, stream>>>(Wk, Wv, wkS, wvS);
    k_kv    <<<dim3(B*NN/16), dim3(512), 0, stream>>>(xf, wkS, wvS, bk, bv,
                                                      tln_g, tln_b, kbuf, vbuf);
    k_rest  <<<dim3(224),     dim3(512), 0, stream>>>(kbuf, vbuf, attF, Wq, out_W, wqS, owS,
                                                      emb, emb_W, emb_b, ssb);
    k_main  <<<dim3(B*T/MR),  dim3(512), 0, stream>>>(x, wqS, bq, ln_g, ln_b, attF, ssb,
                                                      sn_g, sn_b, owS, out_b, out);
}